// Round 2
// baseline (329.346 us; speedup 1.0000x reference)
//
#include <hip/hip_runtime.h>
#include <stdint.h>

// Problem constants (float32 dataset; MFMA in bf16, threshold is 2% of max|ref|)
#define BROWS 16384
#define DDIM  512
#define EEXP  16
#define HDIM  256
#define LDIM  64
#define BM    64
#define BK    64

typedef __bf16  bf16x8  __attribute__((ext_vector_type(8)));
typedef float   floatx4 __attribute__((ext_vector_type(4)));
typedef ushort  ushort8 __attribute__((ext_vector_type(8)));

__device__ __forceinline__ ushort f2bf(float f) {
    uint32_t u = __builtin_bit_cast(uint32_t, f);
    u += 0x7fffu + ((u >> 16) & 1u);   // RNE
    return (ushort)(u >> 16);
}

// ---------------------------------------------------------------------------
// Gating: gates[b][e] fp32, full fp32 math. Block = 256 = 16 rows x 16 experts.
// wg/wn staged in two D-halves so everything fits in 64 KB LDS.
// ---------------------------------------------------------------------------
__global__ __launch_bounds__(256) void gating_kernel(
    const float* __restrict__ x,      // [B][D]
    const float* __restrict__ noise,  // [B][E]
    const float* __restrict__ wg,     // [D][E]
    const float* __restrict__ wn,     // [D][E]
    float* __restrict__ gates)        // [B][E]
{
    __shared__ __align__(16) float xs[16 * DDIM];      // 32 KB
    __shared__ __align__(16) float wgs[256 * EEXP];    // 16 KB
    __shared__ __align__(16) float wns[256 * EEXP];    // 16 KB

    const int tid  = threadIdx.x;
    const int row0 = blockIdx.x * 16;

    // stage 16 rows of x: 8192 floats = 2048 float4
    #pragma unroll
    for (int p = 0; p < 8; ++p) {
        int i4 = p * 256 + tid;
        reinterpret_cast<float4*>(xs)[i4] =
            reinterpret_cast<const float4*>(x + (size_t)row0 * DDIM)[i4];
    }

    const int r = tid >> 4;    // local row 0..15
    const int e = tid & 15;    // expert

    float accg = 0.f, accn = 0.f;
    for (int half = 0; half < 2; ++half) {
        if (half) __syncthreads();   // previous-half reads done
        #pragma unroll
        for (int p = 0; p < 4; ++p) {
            int i4 = p * 256 + tid;
            reinterpret_cast<float4*>(wgs)[i4] =
                reinterpret_cast<const float4*>(wg + half * 256 * EEXP)[i4];
            reinterpret_cast<float4*>(wns)[i4] =
                reinterpret_cast<const float4*>(wn + half * 256 * EEXP)[i4];
        }
        __syncthreads();
        #pragma unroll 8
        for (int d = 0; d < 256; ++d) {
            float xv = xs[r * DDIM + half * 256 + d];
            accg += xv * wgs[d * EEXP + e];
            accn += xv * wns[d * EEXP + e];
        }
    }

    // softplus (stable): max(z,0) + log1p(exp(-|z|))
    float sp = fmaxf(accn, 0.f) + log1pf(expf(-fabsf(accn)));
    float stddev = sp + 0.01f;
    float nz = noise[(size_t)(row0 + r) * EEXP + e];
    float z = accg + nz * stddev;

    // softmax across the 16-lane expert group
    float m = z;
    #pragma unroll
    for (int mask = 8; mask >= 1; mask >>= 1)
        m = fmaxf(m, __shfl_xor(m, mask, 16));
    float ez = expf(z - m);
    float s = ez;
    #pragma unroll
    for (int mask = 8; mask >= 1; mask >>= 1)
        s += __shfl_xor(s, mask, 16);
    float logit = ez / s;

    float lsum = logit;
    #pragma unroll
    for (int mask = 8; mask >= 1; mask >>= 1)
        lsum += __shfl_xor(lsum, mask, 16);
    float mean = lsum * (1.0f / 16.0f) - 1e-8f;

    float gate = (logit >= mean) ? logit : 0.0f;
    float denom = gate;
    #pragma unroll
    for (int mask = 8; mask >= 1; mask >>= 1)
        denom += __shfl_xor(denom, mask, 16);

    gates[(size_t)(row0 + r) * EEXP + e] = gate / denom;
}

// ---------------------------------------------------------------------------
// Transpose + f32->bf16: src f32 [E][R][C] -> dst bf16 [E][C][R].
// ---------------------------------------------------------------------------
__global__ __launch_bounds__(256) void transpose_cvt(
    const float* __restrict__ src, ushort* __restrict__ dst, int R, int C)
{
    __shared__ float tile[32][33];
    const int ei = blockIdx.z;
    const int c0 = blockIdx.x * 32, r0 = blockIdx.y * 32;
    const int tx = threadIdx.x & 31, ty = threadIdx.x >> 5;   // ty 0..7
    const float* s = src + (size_t)ei * R * C;
    ushort* d = dst + (size_t)ei * R * C;

    #pragma unroll
    for (int i = 0; i < 4; ++i) {
        int rr = ty + i * 8;
        tile[rr][tx] = s[(size_t)(r0 + rr) * C + c0 + tx];
    }
    __syncthreads();
    #pragma unroll
    for (int i = 0; i < 4; ++i) {
        int cc = ty + i * 8;
        d[(size_t)(c0 + cc) * R + r0 + tx] = f2bf(tile[tx][cc]);
    }
}

// ---------------------------------------------------------------------------
// Fused expert MLP per (64-row tile, expert):
//   h = tanh(x_tile @ W1[e] + b1[e])  [64 x 256]   (K = 512, bf16 MFMA)
//   y = (h @ W2[e] + b2[e]) * gates   [64 x 64]    (K = 256, bf16 MFMA)
// W1T bf16 [E][H][D], W2T bf16 [E][L][H] (K-contiguous). x converted on stage.
// ---------------------------------------------------------------------------
__global__ __launch_bounds__(256, 2) void expert_kernel(
    const float*  __restrict__ x,      // [B][D] f32
    const float*  __restrict__ gates,  // [B][E] f32
    const ushort* __restrict__ W1T,    // [E][H][D] bf16
    const float*  __restrict__ b1,     // [E][H] f32
    const ushort* __restrict__ W2T,    // [E][L][H] bf16
    const float*  __restrict__ b2,     // [E][L] f32
    float* __restrict__ out)           // [B][E][L] f32
{
    // 64 KB LDS. Phase A: A-tile [64][64] @0, B-tile [256][64] @4096
    //           Phase B: h [64][256] @0,  W2 [64][256] @16384
    __shared__ __align__(16) ushort lds[32768];

    const int tid  = threadIdx.x;
    const int lane = tid & 63;
    const int wave = tid >> 6;
    const int row0 = blockIdx.x * BM;
    const int e    = blockIdx.y;

    const int lr = lane & 15;          // MFMA m/n index
    const int kq = (lane >> 4) * 8;    // MFMA k-offset
    const int rq = (lane >> 4) * 4;    // MFMA C-row quad offset

    const float*  xA = x + (size_t)row0 * DDIM;
    const ushort* w1 = W1T + (size_t)e * HDIM * DDIM;

    floatx4 acc[4][4] = {};

    for (int k0 = 0; k0 < DDIM; k0 += BK) {
        // stage A tile 64x64: convert f32 -> bf16 (8 elems/thread/pass)
        #pragma unroll
        for (int p = 0; p < 2; ++p) {
            int idx = (p * 256 + tid) * 8;
            int rr = idx >> 6, cc = idx & 63;
            const float* xp = &xA[(size_t)rr * DDIM + k0 + cc];
            float4 f0 = *reinterpret_cast<const float4*>(xp);
            float4 f1 = *reinterpret_cast<const float4*>(xp + 4);
            ushort8 t;
            t[0]=f2bf(f0.x); t[1]=f2bf(f0.y); t[2]=f2bf(f0.z); t[3]=f2bf(f0.w);
            t[4]=f2bf(f1.x); t[5]=f2bf(f1.y); t[6]=f2bf(f1.z); t[7]=f2bf(f1.w);
            *reinterpret_cast<ushort8*>(&lds[idx]) = t;
        }
        // stage B tile (W1T, already bf16): 256x64 = 16384 ushort
        #pragma unroll
        for (int p = 0; p < 8; ++p) {
            int idx = (p * 256 + tid) * 8;
            int rr = idx >> 6, cc = idx & 63;
            *reinterpret_cast<uint4*>(&lds[4096 + idx]) =
                *reinterpret_cast<const uint4*>(&w1[(size_t)rr * DDIM + k0 + cc]);
        }
        __syncthreads();

        #pragma unroll
        for (int s = 0; s < 2; ++s) {
            bf16x8 af[4], bf[4];
            #pragma unroll
            for (int i = 0; i < 4; ++i)
                af[i] = *reinterpret_cast<const bf16x8*>(
                    &lds[(i * 16 + lr) * 64 + s * 32 + kq]);
            #pragma unroll
            for (int j = 0; j < 4; ++j)
                bf[j] = *reinterpret_cast<const bf16x8*>(
                    &lds[4096 + (wave * 64 + j * 16 + lr) * 64 + s * 32 + kq]);
            #pragma unroll
            for (int i = 0; i < 4; ++i)
                #pragma unroll
                for (int j = 0; j < 4; ++j)
                    acc[i][j] = __builtin_amdgcn_mfma_f32_16x16x32_bf16(
                        af[i], bf[j], acc[i][j], 0, 0, 0);
        }
        __syncthreads();
    }

    // Phase A epilogue: h = tanh(acc + b1) -> bf16 into lds[0..16384) as [64][256]
    float b1v[4];
    #pragma unroll
    for (int j = 0; j < 4; ++j)
        b1v[j] = b1[e * HDIM + wave * 64 + j * 16 + lr];

    #pragma unroll
    for (int i = 0; i < 4; ++i)
        #pragma unroll
        for (int j = 0; j < 4; ++j) {
            int col = wave * 64 + j * 16 + lr;
            #pragma unroll
            for (int rr = 0; rr < 4; ++rr) {
                int row = i * 16 + rq + rr;
                float v = tanhf(acc[i][j][rr] + b1v[j]);
                lds[row * 256 + col] = f2bf(v);
            }
        }

    // stage W2T[e] (bf16): 64x256 = 16384 ushort at lds[16384..)
    const ushort* w2 = W2T + (size_t)e * LDIM * HDIM;
    #pragma unroll
    for (int p = 0; p < 8; ++p) {
        int idx = (p * 256 + tid) * 8;
        *reinterpret_cast<uint4*>(&lds[16384 + idx]) =
            *reinterpret_cast<const uint4*>(&w2[idx]);
    }
    __syncthreads();

    // Phase B: y[64][64]; wave handles rows [wave*16, wave*16+16)
    floatx4 acc2[4] = {};
    #pragma unroll
    for (int s = 0; s < 8; ++s) {
        bf16x8 af = *reinterpret_cast<const bf16x8*>(
            &lds[(wave * 16 + lr) * 256 + s * 32 + kq]);
        #pragma unroll
        for (int j = 0; j < 4; ++j) {
            bf16x8 bf = *reinterpret_cast<const bf16x8*>(
                &lds[16384 + (j * 16 + lr) * 256 + s * 32 + kq]);
            acc2[j] = __builtin_amdgcn_mfma_f32_16x16x32_bf16(
                af, bf, acc2[j], 0, 0, 0);
        }
    }

    // Epilogue: f32 bias + gate scale, f32 store
    #pragma unroll
    for (int j = 0; j < 4; ++j) {
        float b2v = b2[e * LDIM + j * 16 + lr];
        #pragma unroll
        for (int rr = 0; rr < 4; ++rr) {
            int row = wave * 16 + rq + rr;
            float g = gates[(size_t)(row0 + row) * EEXP + e];
            out[(size_t)(row0 + row) * EEXP * LDIM + e * LDIM + j * 16 + lr] =
                (acc2[j][rr] + b2v) * g;
        }
    }
}

// ---------------------------------------------------------------------------
extern "C" void kernel_launch(void* const* d_in, const int* in_sizes, int n_in,
                              void* d_out, int out_size, void* d_ws, size_t ws_size,
                              hipStream_t stream) {
    (void)in_sizes; (void)n_in; (void)out_size; (void)ws_size;
    const float* x     = (const float*)d_in[0];
    const float* noise = (const float*)d_in[1];
    const float* wg    = (const float*)d_in[2];
    const float* wn    = (const float*)d_in[3];
    const float* W1    = (const float*)d_in[4];
    const float* b1    = (const float*)d_in[5];
    const float* W2    = (const float*)d_in[6];
    const float* b2    = (const float*)d_in[7];
    float* out = (float*)d_out;

    char* ws = (char*)d_ws;
    float*  gates = (float*)ws;                    // 16384*16*4 = 1 MiB
    ushort* W1T   = (ushort*)(ws + (1 << 20));     // 16*256*512*2 = 4 MiB
    ushort* W2T   = (ushort*)(ws + (5 << 20));     // 16*64*256*2 = 0.5 MiB

    gating_kernel<<<BROWS / 16, 256, 0, stream>>>(x, noise, wg, wn, gates);
    transpose_cvt<<<dim3(HDIM / 32, DDIM / 32, EEXP), 256, 0, stream>>>(W1, W1T, DDIM, HDIM);
    transpose_cvt<<<dim3(LDIM / 32, HDIM / 32, EEXP), 256, 0, stream>>>(W2, W2T, HDIM, LDIM);
    expert_kernel<<<dim3(BROWS / BM, EEXP), 256, 0, stream>>>(
        x, gates, W1T, b1, W2T, b2, out);
}

// Round 3
// 267.626 us; speedup vs baseline: 1.2306x; 1.2306x over previous
//
#include <hip/hip_runtime.h>
#include <stdint.h>

#define BROWS 16384
#define DDIM  512
#define EEXP  16
#define HDIM  256
#define LDIM  64

typedef __bf16  bf16x8  __attribute__((ext_vector_type(8)));
typedef float   floatx4 __attribute__((ext_vector_type(4)));
typedef ushort  ushort8 __attribute__((ext_vector_type(8)));
typedef unsigned int u32;

__device__ __forceinline__ ushort f2bf(float f) {
    uint32_t u = __builtin_bit_cast(uint32_t, f);
    u += 0x7fffu + ((u >> 16) & 1u);   // RNE
    return (ushort)(u >> 16);
}

__device__ __forceinline__ void gl_lds16(const void* g, void* l) {
    __builtin_amdgcn_global_load_lds(
        (const __attribute__((address_space(1))) u32*)g,
        (__attribute__((address_space(3))) u32*)l, 16, 0, 0);
}

// ---------------------------------------------------------------------------
// x f32 -> bf16, XOR-swizzled: 16B group g of 64-elem K-block stored at g^(row&7)
// ---------------------------------------------------------------------------
__global__ __launch_bounds__(256) void cvt_swizzle_x(
    const float* __restrict__ x, ushort* __restrict__ xbf)
{
    int gid = blockIdx.x * 256 + threadIdx.x;   // 1M threads, 8 elems each
    int row = gid >> 6;
    int gi  = gid & 63;
    int kb  = gi >> 3, g = gi & 7;
    const float* src = &x[(size_t)row * DDIM + kb * 64 + g * 8];
    float4 f0 = *reinterpret_cast<const float4*>(src);
    float4 f1 = *reinterpret_cast<const float4*>(src + 4);
    ushort8 t;
    t[0]=f2bf(f0.x); t[1]=f2bf(f0.y); t[2]=f2bf(f0.z); t[3]=f2bf(f0.w);
    t[4]=f2bf(f1.x); t[5]=f2bf(f1.y); t[6]=f2bf(f1.z); t[7]=f2bf(f1.w);
    int gp = g ^ (row & 7);
    *reinterpret_cast<ushort8*>(&xbf[(size_t)row * DDIM + kb * 64 + gp * 8]) = t;
}

// ---------------------------------------------------------------------------
// Gating (f32): 64 rows/block, thread = (rg 0..15, og 0..15): 4 rows x (wg,wn).
// Weights transposed in LDS with stride 132 (pad 4) -> conflict-free b128 reads.
// ---------------------------------------------------------------------------
__global__ __launch_bounds__(256) void gating_kernel(
    const float* __restrict__ x,      // [B][D]
    const float* __restrict__ noise,  // [B][E]
    const float* __restrict__ wg,     // [D][E]
    const float* __restrict__ wn,     // [D][E]
    float* __restrict__ gates)        // [B][E]
{
    __shared__ __align__(16) float xs[64 * 132];    // 33 KB
    __shared__ __align__(16) float wTg[16 * 132];   // 8.25 KB
    __shared__ __align__(16) float wTn[16 * 132];   // 8.25 KB

    const int t    = threadIdx.x;
    const int row0 = blockIdx.x * 64;
    const int og   = t & 15, rg = t >> 4;

    floatx4 accg4[4] = {}, accn4[4] = {};

    for (int ch = 0; ch < 4; ++ch) {
        const int k0 = ch * 128;
        __syncthreads();   // previous chunk's reads done before restage
        {   // stage xs[64][128]
            int r = t >> 2, c = (t & 3) * 32;
            const float* src = &x[(size_t)(row0 + r) * DDIM + k0 + c];
            float* dst = &xs[r * 132 + c];
            #pragma unroll
            for (int i = 0; i < 8; ++i)
                *reinterpret_cast<float4*>(dst + i * 4) =
                    *reinterpret_cast<const float4*>(src + i * 4);
        }
        {   // stage wTg/wTn transposed: thread reads row d=k0+(t>>1), experts e0..e0+7
            int d = t >> 1, e0 = (t & 1) * 8;
            float4 a0 = *reinterpret_cast<const float4*>(&wg[(size_t)(k0 + d) * EEXP + e0]);
            float4 a1 = *reinterpret_cast<const float4*>(&wg[(size_t)(k0 + d) * EEXP + e0 + 4]);
            float4 b0 = *reinterpret_cast<const float4*>(&wn[(size_t)(k0 + d) * EEXP + e0]);
            float4 b1 = *reinterpret_cast<const float4*>(&wn[(size_t)(k0 + d) * EEXP + e0 + 4]);
            wTg[(e0+0)*132+d]=a0.x; wTg[(e0+1)*132+d]=a0.y; wTg[(e0+2)*132+d]=a0.z; wTg[(e0+3)*132+d]=a0.w;
            wTg[(e0+4)*132+d]=a1.x; wTg[(e0+5)*132+d]=a1.y; wTg[(e0+6)*132+d]=a1.z; wTg[(e0+7)*132+d]=a1.w;
            wTn[(e0+0)*132+d]=b0.x; wTn[(e0+1)*132+d]=b0.y; wTn[(e0+2)*132+d]=b0.z; wTn[(e0+3)*132+d]=b0.w;
            wTn[(e0+4)*132+d]=b1.x; wTn[(e0+5)*132+d]=b1.y; wTn[(e0+6)*132+d]=b1.z; wTn[(e0+7)*132+d]=b1.w;
        }
        __syncthreads();

        #pragma unroll 8
        for (int d4 = 0; d4 < 32; ++d4) {
            floatx4 wgv = *reinterpret_cast<const floatx4*>(&wTg[og * 132 + d4 * 4]);
            floatx4 wnv = *reinterpret_cast<const floatx4*>(&wTn[og * 132 + d4 * 4]);
            #pragma unroll
            for (int rr = 0; rr < 4; ++rr) {
                floatx4 xv = *reinterpret_cast<const floatx4*>(&xs[(rg * 4 + rr) * 132 + d4 * 4]);
                accg4[rr] += xv * wgv;
                accn4[rr] += xv * wnv;
            }
        }
    }

    #pragma unroll
    for (int rr = 0; rr < 4; ++rr) {
        const int row = row0 + rg * 4 + rr;
        float accg = accg4[rr][0] + accg4[rr][1] + accg4[rr][2] + accg4[rr][3];
        float accn = accn4[rr][0] + accn4[rr][1] + accn4[rr][2] + accn4[rr][3];

        float sp = fmaxf(accn, 0.f) + log1pf(expf(-fabsf(accn)));
        float stddev = sp + 0.01f;
        float nz = noise[(size_t)row * EEXP + og];
        float z = accg + nz * stddev;

        float m = z;
        #pragma unroll
        for (int mask = 8; mask >= 1; mask >>= 1)
            m = fmaxf(m, __shfl_xor(m, mask, 16));
        float ez = expf(z - m);
        float s = ez;
        #pragma unroll
        for (int mask = 8; mask >= 1; mask >>= 1)
            s += __shfl_xor(s, mask, 16);
        float logit = ez / s;

        float lsum = logit;
        #pragma unroll
        for (int mask = 8; mask >= 1; mask >>= 1)
            lsum += __shfl_xor(lsum, mask, 16);
        float mean = lsum * (1.0f / 16.0f) - 1e-8f;

        float gate = (logit >= mean) ? logit : 0.0f;
        float denom = gate;
        #pragma unroll
        for (int mask = 8; mask >= 1; mask >>= 1)
            denom += __shfl_xor(denom, mask, 16);

        gates[(size_t)row * EEXP + og] = gate / denom;
    }
}

// ---------------------------------------------------------------------------
// Transpose + cvt f32->bf16: src [E][R][C] -> dst [E][C][R]; optional XOR swizzle
// of 16B groups within each 64-elem block of the output row (for W1T).
// ---------------------------------------------------------------------------
__global__ __launch_bounds__(256) void transpose_cvt(
    const float* __restrict__ src, ushort* __restrict__ dst, int R, int C, int swz)
{
    __shared__ float tile[32][33];
    const int ei = blockIdx.z;
    const int c0 = blockIdx.x * 32, r0 = blockIdx.y * 32;
    const int tx = threadIdx.x & 31, ty = threadIdx.x >> 5;
    const float* s = src + (size_t)ei * R * C;
    ushort* d = dst + (size_t)ei * R * C;

    #pragma unroll
    for (int i = 0; i < 4; ++i) {
        int rr = ty + i * 8;
        tile[rr][tx] = s[(size_t)(r0 + rr) * C + c0 + tx];
    }
    __syncthreads();
    #pragma unroll
    for (int i = 0; i < 4; ++i) {
        int cc = ty + i * 8;
        int h = c0 + cc;            // output row
        int col = r0 + tx;          // output col
        int col2 = col;
        if (swz) {
            int g = (col >> 3) & 7;
            col2 = (col & ~63) | ((g ^ (h & 7)) << 3) | (col & 7);
        }
        d[(size_t)h * R + col2] = f2bf(tile[tx][cc]);
    }
}

// ---------------------------------------------------------------------------
// Fused expert MLP. 40 KB LDS -> 4 blocks/CU. A/B staged via global_load_lds
// from pre-swizzled bf16 layouts; W2 fragments read directly from global (L2).
// ---------------------------------------------------------------------------
__global__ __launch_bounds__(256, 4) void expert_kernel(
    const ushort* __restrict__ xbf,    // [B][D] bf16, swizzled
    const float*  __restrict__ gates,  // [B][E]
    const ushort* __restrict__ W1T,    // [E][H][D] bf16, swizzled
    const float*  __restrict__ b1,     // [E][H]
    const ushort* __restrict__ W2T,    // [E][L][H] bf16, linear
    const float*  __restrict__ b2,     // [E][L]
    float* __restrict__ out)           // [B][E][L]
{
    __shared__ __align__(16) ushort lds[20480];  // A [0,4096) B [4096,20480); h [0,16384)

    const int tid  = threadIdx.x;
    const int lane = tid & 63;
    const int wave = tid >> 6;
    const int bx   = blockIdx.x;
    const int e    = bx & 15;
    const int row0 = (bx >> 4) * 64;

    const int lr = lane & 15;
    const int q  = lane >> 4;
    const int kq = q * 8;
    const int rq = q * 4;
    const int la = lane >> 3, lb = lane & 7;   // staging lane split

    const char* xg = (const char*)xbf + (size_t)row0 * 1024;
    const char* w1 = (const char*)W1T + (size_t)e * HDIM * 1024;

    floatx4 acc[4][4] = {};

    for (int kb = 0; kb < 8; ++kb) {
        const int koff = kb * 128;   // byte offset within 1024-B row
        #pragma unroll
        for (int p = 0; p < 2; ++p) {   // A tile: 8 KB, chunk = 1 KB
            int c = wave * 2 + p;
            gl_lds16(xg + (size_t)(c * 8 + la) * 1024 + koff + lb * 16, &lds[c * 512]);
        }
        #pragma unroll
        for (int p = 0; p < 8; ++p) {   // B tile: 32 KB
            int c = wave * 8 + p;
            gl_lds16(w1 + (size_t)(c * 8 + la) * 1024 + koff + lb * 16, &lds[4096 + c * 512]);
        }
        __syncthreads();

        #pragma unroll
        for (int s = 0; s < 2; ++s) {
            const int g = s * 4 + q;
            bf16x8 af[4], bfr[4];
            #pragma unroll
            for (int i = 0; i < 4; ++i) {
                int r = i * 16 + lr;
                af[i] = *reinterpret_cast<const bf16x8*>(&lds[r * 64 + ((g ^ (r & 7)) << 3)]);
            }
            #pragma unroll
            for (int j = 0; j < 4; ++j) {
                int r = wave * 64 + j * 16 + lr;
                bfr[j] = *reinterpret_cast<const bf16x8*>(&lds[4096 + r * 64 + ((g ^ (r & 7)) << 3)]);
            }
            #pragma unroll
            for (int i = 0; i < 4; ++i)
                #pragma unroll
                for (int j = 0; j < 4; ++j)
                    acc[i][j] = __builtin_amdgcn_mfma_f32_16x16x32_bf16(
                        af[i], bfr[j], acc[i][j], 0, 0, 0);
        }
        __syncthreads();
    }

    // h = tanh(acc + b1) -> bf16, swizzled [64][256] at lds[0..16384)
    float b1v[4];
    #pragma unroll
    for (int j = 0; j < 4; ++j)
        b1v[j] = b1[e * HDIM + wave * 64 + j * 16 + lr];

    #pragma unroll
    for (int i = 0; i < 4; ++i)
        #pragma unroll
        for (int j = 0; j < 4; ++j) {
            int c = wave * 64 + j * 16 + lr;
            int gg = c >> 3;
            #pragma unroll
            for (int rr = 0; rr < 4; ++rr) {
                int r = i * 16 + rq + rr;
                float v = tanhf(acc[i][j][rr] + b1v[j]);
                lds[r * 256 + (((gg & 24) | ((gg & 7) ^ (r & 7))) << 3) + (c & 7)] = f2bf(v);
            }
        }
    __syncthreads();

    // Phase B: y[64][64], wave rows [wave*16, +16); W2 frags direct from global
    const ushort* w2 = W2T + (size_t)e * LDIM * HDIM;
    floatx4 acc2[4] = {};
    #pragma unroll
    for (int s = 0; s < 8; ++s) {
        int r = wave * 16 + lr;
        int g = s * 4 + q;
        bf16x8 af = *reinterpret_cast<const bf16x8*>(
            &lds[r * 256 + (((g & 24) | ((g & 7) ^ (r & 7))) << 3)]);
        #pragma unroll
        for (int j = 0; j < 4; ++j) {
            bf16x8 bfr = *reinterpret_cast<const bf16x8*>(
                &w2[(size_t)(j * 16 + lr) * HDIM + s * 32 + kq]);
            acc2[j] = __builtin_amdgcn_mfma_f32_16x16x32_bf16(af, bfr, acc2[j], 0, 0, 0);
        }
    }

    #pragma unroll
    for (int j = 0; j < 4; ++j) {
        float b2v = b2[e * LDIM + j * 16 + lr];
        #pragma unroll
        for (int rr = 0; rr < 4; ++rr) {
            int row = wave * 16 + rq + rr;
            float gsc = gates[(size_t)(row0 + row) * EEXP + e];
            out[(size_t)(row0 + row) * EEXP * LDIM + e * LDIM + j * 16 + lr] =
                (acc2[j][rr] + b2v) * gsc;
        }
    }
}

// ---------------------------------------------------------------------------
extern "C" void kernel_launch(void* const* d_in, const int* in_sizes, int n_in,
                              void* d_out, int out_size, void* d_ws, size_t ws_size,
                              hipStream_t stream) {
    (void)in_sizes; (void)n_in; (void)out_size; (void)ws_size;
    const float* x     = (const float*)d_in[0];
    const float* noise = (const float*)d_in[1];
    const float* wg    = (const float*)d_in[2];
    const float* wn    = (const float*)d_in[3];
    const float* W1    = (const float*)d_in[4];
    const float* b1    = (const float*)d_in[5];
    const float* W2    = (const float*)d_in[6];
    const float* b2    = (const float*)d_in[7];
    float* out = (float*)d_out;

    char* ws = (char*)d_ws;
    float*  gates = (float*)ws;                    // 1 MiB
    ushort* W1T   = (ushort*)(ws + (1 << 20));     // 4 MiB
    ushort* W2T   = (ushort*)(ws + (5 << 20));     // 0.5 MiB
    ushort* xbf   = (ushort*)(ws + (6 << 20));     // 16 MiB

    cvt_swizzle_x<<<(BROWS * DDIM / 8) / 256, 256, 0, stream>>>(x, xbf);
    gating_kernel<<<BROWS / 64, 256, 0, stream>>>(x, noise, wg, wn, gates);
    transpose_cvt<<<dim3(HDIM / 32, DDIM / 32, EEXP), 256, 0, stream>>>(W1, W1T, DDIM, HDIM, 1);
    transpose_cvt<<<dim3(LDIM / 32, HDIM / 32, EEXP), 256, 0, stream>>>(W2, W2T, HDIM, LDIM, 0);
    expert_kernel<<<(BROWS / 64) * EEXP, 256, 0, stream>>>(
        xbf, gates, W1T, b1, W2T, b2, out);
}

// Round 4
// 255.728 us; speedup vs baseline: 1.2879x; 1.0465x over previous
//
#include <hip/hip_runtime.h>
#include <stdint.h>

#define BROWS 16384
#define DDIM  512
#define EEXP  16
#define HDIM  256
#define LDIM  64

typedef __bf16  bf16x8  __attribute__((ext_vector_type(8)));
typedef float   floatx4 __attribute__((ext_vector_type(4)));
typedef ushort  ushort8 __attribute__((ext_vector_type(8)));
typedef unsigned int u32;

__device__ __forceinline__ ushort f2bf(float f) {
    uint32_t u = __builtin_bit_cast(uint32_t, f);
    u += 0x7fffu + ((u >> 16) & 1u);   // RNE
    return (ushort)(u >> 16);
}

// tanh(x) = 1 - 2/(exp2(2x*log2e)+1): v_mul, v_exp, v_add, v_rcp, v_fma.
// Saturates correctly for |x| large; rel err ~1e-6 (<< bf16 quantization).
__device__ __forceinline__ float fast_tanh(float x) {
    float e = __builtin_amdgcn_exp2f(x * 2.8853900817779268f);
    return 1.0f - 2.0f * __builtin_amdgcn_rcpf(e + 1.0f);
}

__device__ __forceinline__ void gl_lds16(const void* g, void* l) {
    __builtin_amdgcn_global_load_lds(
        (const __attribute__((address_space(1))) u32*)g,
        (__attribute__((address_space(3))) u32*)l, 16, 0, 0);
}

// ---------------------------------------------------------------------------
// Gating (f32) + fused x f32->bf16 swizzled conversion.
// 64 rows/block; thread = (rg 0..15, og 0..15): 4 rows x (wg,wn) each.
// While staging xs chunks, the same registers are converted to bf16 and
// written to xbf with the XOR-8 group swizzle the expert kernel expects.
// ---------------------------------------------------------------------------
__global__ __launch_bounds__(256) void gating_kernel(
    const float* __restrict__ x,      // [B][D]
    const float* __restrict__ noise,  // [B][E]
    const float* __restrict__ wg,     // [D][E]
    const float* __restrict__ wn,     // [D][E]
    float* __restrict__ gates,        // [B][E]
    ushort* __restrict__ xbf)         // [B][D] bf16 swizzled
{
    __shared__ __align__(16) float xs[64 * 132];    // 33 KB
    __shared__ __align__(16) float wTg[16 * 132];   // 8.25 KB
    __shared__ __align__(16) float wTn[16 * 132];   // 8.25 KB

    const int t    = threadIdx.x;
    const int row0 = blockIdx.x * 64;
    const int og   = t & 15, rg = t >> 4;

    floatx4 accg4[4] = {}, accn4[4] = {};

    for (int ch = 0; ch < 4; ++ch) {
        const int k0 = ch * 128;
        __syncthreads();   // previous chunk's reads done before restage
        {   // stage xs[64][128] + fused bf16 swizzled writeback
            int r = t >> 2, c = (t & 3) * 32;
            const float* src = &x[(size_t)(row0 + r) * DDIM + k0 + c];
            float4 f[8];
            #pragma unroll
            for (int i = 0; i < 8; ++i)
                f[i] = reinterpret_cast<const float4*>(src)[i];
            float* dst = &xs[r * 132 + c];
            #pragma unroll
            for (int i = 0; i < 8; ++i)
                reinterpret_cast<float4*>(dst)[i] = f[i];

            const int row = row0 + r;
            const int sw  = r & 7;
            #pragma unroll
            for (int i = 0; i < 4; ++i) {
                int cb = k0 + c + i * 8;
                int kb = cb >> 6;
                int g  = (cb >> 3) & 7;
                int gp = g ^ sw;
                float4 a = f[i * 2], b = f[i * 2 + 1];
                ushort8 t8;
                t8[0]=f2bf(a.x); t8[1]=f2bf(a.y); t8[2]=f2bf(a.z); t8[3]=f2bf(a.w);
                t8[4]=f2bf(b.x); t8[5]=f2bf(b.y); t8[6]=f2bf(b.z); t8[7]=f2bf(b.w);
                *reinterpret_cast<ushort8*>(&xbf[(size_t)row * DDIM + kb * 64 + gp * 8]) = t8;
            }
        }
        {   // stage wTg/wTn transposed (pad 132 -> conflict-free reads)
            int d = t >> 1, e0 = (t & 1) * 8;
            float4 a0 = *reinterpret_cast<const float4*>(&wg[(size_t)(k0 + d) * EEXP + e0]);
            float4 a1 = *reinterpret_cast<const float4*>(&wg[(size_t)(k0 + d) * EEXP + e0 + 4]);
            float4 b0 = *reinterpret_cast<const float4*>(&wn[(size_t)(k0 + d) * EEXP + e0]);
            float4 b1 = *reinterpret_cast<const float4*>(&wn[(size_t)(k0 + d) * EEXP + e0 + 4]);
            wTg[(e0+0)*132+d]=a0.x; wTg[(e0+1)*132+d]=a0.y; wTg[(e0+2)*132+d]=a0.z; wTg[(e0+3)*132+d]=a0.w;
            wTg[(e0+4)*132+d]=a1.x; wTg[(e0+5)*132+d]=a1.y; wTg[(e0+6)*132+d]=a1.z; wTg[(e0+7)*132+d]=a1.w;
            wTn[(e0+0)*132+d]=b0.x; wTn[(e0+1)*132+d]=b0.y; wTn[(e0+2)*132+d]=b0.z; wTn[(e0+3)*132+d]=b0.w;
            wTn[(e0+4)*132+d]=b1.x; wTn[(e0+5)*132+d]=b1.y; wTn[(e0+6)*132+d]=b1.z; wTn[(e0+7)*132+d]=b1.w;
        }
        __syncthreads();

        #pragma unroll 8
        for (int d4 = 0; d4 < 32; ++d4) {
            floatx4 wgv = *reinterpret_cast<const floatx4*>(&wTg[og * 132 + d4 * 4]);
            floatx4 wnv = *reinterpret_cast<const floatx4*>(&wTn[og * 132 + d4 * 4]);
            #pragma unroll
            for (int rr = 0; rr < 4; ++rr) {
                floatx4 xv = *reinterpret_cast<const floatx4*>(&xs[(rg * 4 + rr) * 132 + d4 * 4]);
                accg4[rr] += xv * wgv;
                accn4[rr] += xv * wnv;
            }
        }
    }

    #pragma unroll
    for (int rr = 0; rr < 4; ++rr) {
        const int row = row0 + rg * 4 + rr;
        float accg = accg4[rr][0] + accg4[rr][1] + accg4[rr][2] + accg4[rr][3];
        float accn = accn4[rr][0] + accn4[rr][1] + accn4[rr][2] + accn4[rr][3];

        // keep libcall-precision softplus here: gate threshold flips are the risk
        float sp = fmaxf(accn, 0.f) + log1pf(expf(-fabsf(accn)));
        float stddev = sp + 0.01f;
        float nz = noise[(size_t)row * EEXP + og];
        float z = accg + nz * stddev;

        float m = z;
        #pragma unroll
        for (int mask = 8; mask >= 1; mask >>= 1)
            m = fmaxf(m, __shfl_xor(m, mask, 16));
        float ez = expf(z - m);
        float s = ez;
        #pragma unroll
        for (int mask = 8; mask >= 1; mask >>= 1)
            s += __shfl_xor(s, mask, 16);
        float logit = ez / s;

        float lsum = logit;
        #pragma unroll
        for (int mask = 8; mask >= 1; mask >>= 1)
            lsum += __shfl_xor(lsum, mask, 16);
        float mean = lsum * (1.0f / 16.0f) - 1e-8f;

        float gate = (logit >= mean) ? logit : 0.0f;
        float denom = gate;
        #pragma unroll
        for (int mask = 8; mask >= 1; mask >>= 1)
            denom += __shfl_xor(denom, mask, 16);

        gates[(size_t)row * EEXP + og] = gate / denom;
    }
}

// ---------------------------------------------------------------------------
// Transpose + cvt f32->bf16: src [E][R][C] -> dst [E][C][R]; optional XOR swizzle
// of 16B groups within each 64-elem block of the output row (for W1T).
// ---------------------------------------------------------------------------
__global__ __launch_bounds__(256) void transpose_cvt(
    const float* __restrict__ src, ushort* __restrict__ dst, int R, int C, int swz)
{
    __shared__ float tile[32][33];
    const int ei = blockIdx.z;
    const int c0 = blockIdx.x * 32, r0 = blockIdx.y * 32;
    const int tx = threadIdx.x & 31, ty = threadIdx.x >> 5;
    const float* s = src + (size_t)ei * R * C;
    ushort* d = dst + (size_t)ei * R * C;

    #pragma unroll
    for (int i = 0; i < 4; ++i) {
        int rr = ty + i * 8;
        tile[rr][tx] = s[(size_t)(r0 + rr) * C + c0 + tx];
    }
    __syncthreads();
    #pragma unroll
    for (int i = 0; i < 4; ++i) {
        int cc = ty + i * 8;
        int h = c0 + cc;            // output row
        int col = r0 + tx;          // output col
        int col2 = col;
        if (swz) {
            int g = (col >> 3) & 7;
            col2 = (col & ~63) | ((g ^ (h & 7)) << 3) | (col & 7);
        }
        d[(size_t)h * R + col2] = f2bf(tile[tx][cc]);
    }
}

// ---------------------------------------------------------------------------
// Fused expert MLP. 40 KB LDS -> 4 blocks/CU. A/B staged via global_load_lds
// from pre-swizzled bf16 layouts; W2 fragments read directly from global (L2).
// ---------------------------------------------------------------------------
__global__ __launch_bounds__(256, 4) void expert_kernel(
    const ushort* __restrict__ xbf,    // [B][D] bf16, swizzled
    const float*  __restrict__ gates,  // [B][E]
    const ushort* __restrict__ W1T,    // [E][H][D] bf16, swizzled
    const float*  __restrict__ b1,     // [E][H]
    const ushort* __restrict__ W2T,    // [E][L][H] bf16, linear
    const float*  __restrict__ b2,     // [E][L]
    float* __restrict__ out)           // [B][E][L]
{
    __shared__ __align__(16) ushort lds[20480];  // A [0,4096) B [4096,20480); h [0,16384)

    const int tid  = threadIdx.x;
    const int lane = tid & 63;
    const int wave = tid >> 6;
    const int bx   = blockIdx.x;
    const int e    = bx & 15;
    const int row0 = (bx >> 4) * 64;

    const int lr = lane & 15;
    const int q  = lane >> 4;
    const int kq = q * 8;
    const int rq = q * 4;
    const int la = lane >> 3, lb = lane & 7;   // staging lane split

    const char* xg = (const char*)xbf + (size_t)row0 * 1024;
    const char* w1 = (const char*)W1T + (size_t)e * HDIM * 1024;

    floatx4 acc[4][4] = {};

    for (int kb = 0; kb < 8; ++kb) {
        const int koff = kb * 128;   // byte offset within 1024-B row
        #pragma unroll
        for (int p = 0; p < 2; ++p) {   // A tile: 8 KB, chunk = 1 KB
            int c = wave * 2 + p;
            gl_lds16(xg + (size_t)(c * 8 + la) * 1024 + koff + lb * 16, &lds[c * 512]);
        }
        #pragma unroll
        for (int p = 0; p < 8; ++p) {   // B tile: 32 KB
            int c = wave * 8 + p;
            gl_lds16(w1 + (size_t)(c * 8 + la) * 1024 + koff + lb * 16, &lds[4096 + c * 512]);
        }
        __syncthreads();

        #pragma unroll
        for (int s = 0; s < 2; ++s) {
            const int g = s * 4 + q;
            bf16x8 af[4], bfr[4];
            #pragma unroll
            for (int i = 0; i < 4; ++i) {
                int r = i * 16 + lr;
                af[i] = *reinterpret_cast<const bf16x8*>(&lds[r * 64 + ((g ^ (r & 7)) << 3)]);
            }
            #pragma unroll
            for (int j = 0; j < 4; ++j) {
                int r = wave * 64 + j * 16 + lr;
                bfr[j] = *reinterpret_cast<const bf16x8*>(&lds[4096 + r * 64 + ((g ^ (r & 7)) << 3)]);
            }
            #pragma unroll
            for (int i = 0; i < 4; ++i)
                #pragma unroll
                for (int j = 0; j < 4; ++j)
                    acc[i][j] = __builtin_amdgcn_mfma_f32_16x16x32_bf16(
                        af[i], bfr[j], acc[i][j], 0, 0, 0);
        }
        __syncthreads();
    }

    // h = fast_tanh(acc + b1) -> bf16, swizzled [64][256] at lds[0..16384)
    float b1v[4];
    #pragma unroll
    for (int j = 0; j < 4; ++j)
        b1v[j] = b1[e * HDIM + wave * 64 + j * 16 + lr];

    #pragma unroll
    for (int i = 0; i < 4; ++i)
        #pragma unroll
        for (int j = 0; j < 4; ++j) {
            int c = wave * 64 + j * 16 + lr;
            int gg = c >> 3;
            #pragma unroll
            for (int rr = 0; rr < 4; ++rr) {
                int r = i * 16 + rq + rr;
                float v = fast_tanh(acc[i][j][rr] + b1v[j]);
                lds[r * 256 + (((gg & 24) | ((gg & 7) ^ (r & 7))) << 3) + (c & 7)] = f2bf(v);
            }
        }
    __syncthreads();

    // Phase B: y[64][64], wave rows [wave*16, +16); W2 frags direct from global
    const ushort* w2 = W2T + (size_t)e * LDIM * HDIM;
    floatx4 acc2[4] = {};
    #pragma unroll
    for (int s = 0; s < 8; ++s) {
        int r = wave * 16 + lr;
        int g = s * 4 + q;
        bf16x8 af = *reinterpret_cast<const bf16x8*>(
            &lds[r * 256 + (((g & 24) | ((g & 7) ^ (r & 7))) << 3)]);
        #pragma unroll
        for (int j = 0; j < 4; ++j) {
            bf16x8 bfr = *reinterpret_cast<const bf16x8*>(
                &w2[(size_t)(j * 16 + lr) * HDIM + s * 32 + kq]);
            acc2[j] = __builtin_amdgcn_mfma_f32_16x16x32_bf16(af, bfr, acc2[j], 0, 0, 0);
        }
    }

    #pragma unroll
    for (int j = 0; j < 4; ++j) {
        float b2v = b2[e * LDIM + j * 16 + lr];
        #pragma unroll
        for (int rr = 0; rr < 4; ++rr) {
            int row = wave * 16 + rq + rr;
            float gsc = gates[(size_t)(row0 + row) * EEXP + e];
            out[(size_t)(row0 + row) * EEXP * LDIM + e * LDIM + j * 16 + lr] =
                (acc2[j][rr] + b2v) * gsc;
        }
    }
}

// ---------------------------------------------------------------------------
extern "C" void kernel_launch(void* const* d_in, const int* in_sizes, int n_in,
                              void* d_out, int out_size, void* d_ws, size_t ws_size,
                              hipStream_t stream) {
    (void)in_sizes; (void)n_in; (void)out_size; (void)ws_size;
    const float* x     = (const float*)d_in[0];
    const float* noise = (const float*)d_in[1];
    const float* wg    = (const float*)d_in[2];
    const float* wn    = (const float*)d_in[3];
    const float* W1    = (const float*)d_in[4];
    const float* b1    = (const float*)d_in[5];
    const float* W2    = (const float*)d_in[6];
    const float* b2    = (const float*)d_in[7];
    float* out = (float*)d_out;

    char* ws = (char*)d_ws;
    float*  gates = (float*)ws;                    // 1 MiB
    ushort* W1T   = (ushort*)(ws + (1 << 20));     // 4 MiB
    ushort* W2T   = (ushort*)(ws + (5 << 20));     // 0.5 MiB
    ushort* xbf   = (ushort*)(ws + (6 << 20));     // 16 MiB

    gating_kernel<<<BROWS / 64, 256, 0, stream>>>(x, noise, wg, wn, gates, xbf);
    transpose_cvt<<<dim3(HDIM / 32, DDIM / 32, EEXP), 256, 0, stream>>>(W1, W1T, DDIM, HDIM, 1);
    transpose_cvt<<<dim3(LDIM / 32, HDIM / 32, EEXP), 256, 0, stream>>>(W2, W2T, HDIM, LDIM, 0);
    expert_kernel<<<(BROWS / 64) * EEXP, 256, 0, stream>>>(
        xbf, gates, W1T, b1, W2T, b2, out);
}

// Round 5
// 219.168 us; speedup vs baseline: 1.5027x; 1.1668x over previous
//
#include <hip/hip_runtime.h>
#include <stdint.h>

#define BROWS 16384
#define DDIM  512
#define EEXP  16
#define HDIM  256
#define LDIM  64
#define BM    128

typedef __bf16  bf16x8  __attribute__((ext_vector_type(8)));
typedef float   floatx4 __attribute__((ext_vector_type(4)));
typedef ushort  ushort8 __attribute__((ext_vector_type(8)));
typedef unsigned int u32;

__device__ __forceinline__ ushort f2bf(float f) {
    uint32_t u = __builtin_bit_cast(uint32_t, f);
    u += 0x7fffu + ((u >> 16) & 1u);   // RNE
    return (ushort)(u >> 16);
}

// tanh(x) = 1 - 2/(exp2(2x*log2e)+1); saturates correctly, rel err ~1e-6.
__device__ __forceinline__ float fast_tanh(float x) {
    float e = __builtin_amdgcn_exp2f(x * 2.8853900817779268f);
    return 1.0f - 2.0f * __builtin_amdgcn_rcpf(e + 1.0f);
}

__device__ __forceinline__ void gl_lds16(const void* g, void* l) {
    __builtin_amdgcn_global_load_lds(
        (const __attribute__((address_space(1))) u32*)g,
        (__attribute__((address_space(3))) u32*)l, 16, 0, 0);
}

// ---------------------------------------------------------------------------
// Gating (f32) + fused x f32->bf16 swizzled conversion. 32 rows/block.
// thread = (rg 0..15, og 0..15): 2 rows x (wg,wn) each.
// ---------------------------------------------------------------------------
__global__ __launch_bounds__(256) void gating_kernel(
    const float* __restrict__ x,      // [B][D]
    const float* __restrict__ noise,  // [B][E]
    const float* __restrict__ wg,     // [D][E]
    const float* __restrict__ wn,     // [D][E]
    float* __restrict__ gates,        // [B][E]
    ushort* __restrict__ xbf)         // [B][D] bf16 swizzled
{
    __shared__ __align__(16) float xs[32 * 132];    // 16.5 KB
    __shared__ __align__(16) float wTg[16 * 132];   // 8.25 KB
    __shared__ __align__(16) float wTn[16 * 132];   // 8.25 KB

    const int t    = threadIdx.x;
    const int row0 = blockIdx.x * 32;
    const int og   = t & 15, rg = t >> 4;

    floatx4 accg4[2] = {}, accn4[2] = {};

    for (int ch = 0; ch < 4; ++ch) {
        const int k0 = ch * 128;
        __syncthreads();   // previous chunk's reads done before restage
        {   // stage xs[32][128] + fused bf16 swizzled writeback
            int r = t >> 3, c = (t & 7) * 16;
            const float* src = &x[(size_t)(row0 + r) * DDIM + k0 + c];
            float4 f[4];
            #pragma unroll
            for (int i = 0; i < 4; ++i)
                f[i] = reinterpret_cast<const float4*>(src)[i];
            float* dst = &xs[r * 132 + c];
            #pragma unroll
            for (int i = 0; i < 4; ++i)
                reinterpret_cast<float4*>(dst)[i] = f[i];

            const int row = row0 + r;
            const int sw  = r & 7;
            #pragma unroll
            for (int i = 0; i < 2; ++i) {
                int cb = k0 + c + i * 8;
                int kb = cb >> 6;
                int g  = (cb >> 3) & 7;
                int gp = g ^ sw;
                float4 a = f[i * 2], b = f[i * 2 + 1];
                ushort8 t8;
                t8[0]=f2bf(a.x); t8[1]=f2bf(a.y); t8[2]=f2bf(a.z); t8[3]=f2bf(a.w);
                t8[4]=f2bf(b.x); t8[5]=f2bf(b.y); t8[6]=f2bf(b.z); t8[7]=f2bf(b.w);
                *reinterpret_cast<ushort8*>(&xbf[(size_t)row * DDIM + kb * 64 + gp * 8]) = t8;
            }
        }
        {   // stage wTg/wTn transposed (pad 132 -> conflict-free reads)
            int d = t >> 1, e0 = (t & 1) * 8;
            float4 a0 = *reinterpret_cast<const float4*>(&wg[(size_t)(k0 + d) * EEXP + e0]);
            float4 a1 = *reinterpret_cast<const float4*>(&wg[(size_t)(k0 + d) * EEXP + e0 + 4]);
            float4 b0 = *reinterpret_cast<const float4*>(&wn[(size_t)(k0 + d) * EEXP + e0]);
            float4 b1 = *reinterpret_cast<const float4*>(&wn[(size_t)(k0 + d) * EEXP + e0 + 4]);
            wTg[(e0+0)*132+d]=a0.x; wTg[(e0+1)*132+d]=a0.y; wTg[(e0+2)*132+d]=a0.z; wTg[(e0+3)*132+d]=a0.w;
            wTg[(e0+4)*132+d]=a1.x; wTg[(e0+5)*132+d]=a1.y; wTg[(e0+6)*132+d]=a1.z; wTg[(e0+7)*132+d]=a1.w;
            wTn[(e0+0)*132+d]=b0.x; wTn[(e0+1)*132+d]=b0.y; wTn[(e0+2)*132+d]=b0.z; wTn[(e0+3)*132+d]=b0.w;
            wTn[(e0+4)*132+d]=b1.x; wTn[(e0+5)*132+d]=b1.y; wTn[(e0+6)*132+d]=b1.z; wTn[(e0+7)*132+d]=b1.w;
        }
        __syncthreads();

        #pragma unroll 8
        for (int d4 = 0; d4 < 32; ++d4) {
            floatx4 wgv = *reinterpret_cast<const floatx4*>(&wTg[og * 132 + d4 * 4]);
            floatx4 wnv = *reinterpret_cast<const floatx4*>(&wTn[og * 132 + d4 * 4]);
            #pragma unroll
            for (int rr = 0; rr < 2; ++rr) {
                floatx4 xv = *reinterpret_cast<const floatx4*>(&xs[(rg * 2 + rr) * 132 + d4 * 4]);
                accg4[rr] += xv * wgv;
                accn4[rr] += xv * wnv;
            }
        }
    }

    #pragma unroll
    for (int rr = 0; rr < 2; ++rr) {
        const int row = row0 + rg * 2 + rr;
        float accg = accg4[rr][0] + accg4[rr][1] + accg4[rr][2] + accg4[rr][3];
        float accn = accn4[rr][0] + accn4[rr][1] + accn4[rr][2] + accn4[rr][3];

        // keep libcall-precision softplus: gate threshold flips are the risk
        float sp = fmaxf(accn, 0.f) + log1pf(expf(-fabsf(accn)));
        float stddev = sp + 0.01f;
        float nz = noise[(size_t)row * EEXP + og];
        float z = accg + nz * stddev;

        float m = z;
        #pragma unroll
        for (int mask = 8; mask >= 1; mask >>= 1)
            m = fmaxf(m, __shfl_xor(m, mask, 16));
        float ez = expf(z - m);
        float s = ez;
        #pragma unroll
        for (int mask = 8; mask >= 1; mask >>= 1)
            s += __shfl_xor(s, mask, 16);
        float logit = ez / s;

        float lsum = logit;
        #pragma unroll
        for (int mask = 8; mask >= 1; mask >>= 1)
            lsum += __shfl_xor(lsum, mask, 16);
        float mean = lsum * (1.0f / 16.0f) - 1e-8f;

        float gate = (logit >= mean) ? logit : 0.0f;
        float denom = gate;
        #pragma unroll
        for (int mask = 8; mask >= 1; mask >>= 1)
            denom += __shfl_xor(denom, mask, 16);

        gates[(size_t)row * EEXP + og] = gate / denom;
    }
}

// ---------------------------------------------------------------------------
// Both weight transposes in ONE launch (block-id range dispatch).
// W1 f32 [E][512][256] -> W1T bf16 [E][256][512] swizzled  (2048 blocks)
// W2 f32 [E][256][64]  -> W2T bf16 [E][64][256]  linear    (256 blocks)
// ---------------------------------------------------------------------------
__global__ __launch_bounds__(256) void transpose_all(
    const float* __restrict__ W1, ushort* __restrict__ W1T,
    const float* __restrict__ W2, ushort* __restrict__ W2T)
{
    __shared__ float tile[32][33];
    int b = blockIdx.x;
    const float* src; ushort* dst; int R, C, c0, r0, swz, ei;
    if (b < 2048) {
        ei = b >> 7; int rem = b & 127;
        c0 = (rem & 7) * 32; r0 = (rem >> 3) * 32;
        R = DDIM; C = HDIM; swz = 1;
        src = W1; dst = W1T;
    } else {
        b -= 2048;
        ei = b >> 4; int rem = b & 15;
        c0 = (rem & 1) * 32; r0 = (rem >> 1) * 32;
        R = HDIM; C = LDIM; swz = 0;
        src = W2; dst = W2T;
    }
    const int tx = threadIdx.x & 31, ty = threadIdx.x >> 5;
    const float* s = src + (size_t)ei * R * C;
    ushort* d = dst + (size_t)ei * R * C;

    #pragma unroll
    for (int i = 0; i < 4; ++i) {
        int rr = ty + i * 8;
        tile[rr][tx] = s[(size_t)(r0 + rr) * C + c0 + tx];
    }
    __syncthreads();
    #pragma unroll
    for (int i = 0; i < 4; ++i) {
        int cc = ty + i * 8;
        int h = c0 + cc;            // output row
        int col = r0 + tx;          // output col
        int col2 = col;
        if (swz) {
            int g = (col >> 3) & 7;
            col2 = (col & ~63) | ((g ^ (h & 7)) << 3) | (col & 7);
        }
        d[(size_t)h * R + col2] = f2bf(tile[tx][cc]);
    }
}

// ---------------------------------------------------------------------------
// Fused expert MLP, BM=128. 64 KB LDS -> 2 blocks/CU. Per (128-row tile, e):
//   GEMM1: h = tanh(x@W1[e]+b1) [128x256], K=512; GEMM2: y=(h@W2[e]+b2)*g [128x64]
// A/B via global_load_lds from pre-swizzled bf16; W2 frags direct from L2.
// ---------------------------------------------------------------------------
__global__ __launch_bounds__(256, 2) void expert_kernel(
    const ushort* __restrict__ xbf,    // [B][D] bf16, swizzled
    const float*  __restrict__ gates,  // [B][E]
    const ushort* __restrict__ W1T,    // [E][H][D] bf16, swizzled
    const float*  __restrict__ b1,     // [E][H]
    const ushort* __restrict__ W2T,    // [E][L][H] bf16, linear
    const float*  __restrict__ b2,     // [E][L]
    float* __restrict__ out)           // [B][E][L]
{
    // 64 KB: phase A: A-tile [128][64] @0 (16 KB), B-tile [256][64] @16384 B (32 KB)
    //        phase B: h [128][256] @0 (64 KB, overlaps)
    __shared__ __align__(16) ushort lds[32768];

    const int tid  = threadIdx.x;
    const int lane = tid & 63;
    const int wave = tid >> 6;
    const int bx   = blockIdx.x;
    const int e    = bx & 15;                 // e fastest: XCD k sees e={k,k+8}
    const int row0 = (bx >> 4) * BM;

    const int lr = lane & 15;
    const int q  = lane >> 4;
    const int kq = q * 8;
    const int rq = q * 4;
    const int la = lane >> 3, lb = lane & 7;  // staging lane split

    const char* xg = (const char*)xbf + (size_t)row0 * 1024;
    const char* w1 = (const char*)W1T + (size_t)e * HDIM * 1024;

    floatx4 acc[8][4] = {};

    for (int kb = 0; kb < 8; ++kb) {
        const int koff = kb * 128;   // byte offset within 1024-B row
        #pragma unroll
        for (int p = 0; p < 4; ++p) {   // A tile: 16 KB, chunk = 1 KB
            int c = wave * 4 + p;
            gl_lds16(xg + (size_t)(c * 8 + la) * 1024 + koff + lb * 16, &lds[c * 512]);
        }
        #pragma unroll
        for (int p = 0; p < 8; ++p) {   // B tile: 32 KB
            int c = wave * 8 + p;
            gl_lds16(w1 + (size_t)(c * 8 + la) * 1024 + koff + lb * 16, &lds[8192 + c * 512]);
        }
        __syncthreads();

        #pragma unroll
        for (int s = 0; s < 2; ++s) {
            const int g = s * 4 + q;
            bf16x8 af[8], bfr[4];
            #pragma unroll
            for (int i = 0; i < 8; ++i) {
                int r = i * 16 + lr;
                af[i] = *reinterpret_cast<const bf16x8*>(&lds[r * 64 + ((g ^ (r & 7)) << 3)]);
            }
            #pragma unroll
            for (int j = 0; j < 4; ++j) {
                int r = wave * 64 + j * 16 + lr;
                bfr[j] = *reinterpret_cast<const bf16x8*>(&lds[8192 + r * 64 + ((g ^ (r & 7)) << 3)]);
            }
            #pragma unroll
            for (int i = 0; i < 8; ++i)
                #pragma unroll
                for (int j = 0; j < 4; ++j)
                    acc[i][j] = __builtin_amdgcn_mfma_f32_16x16x32_bf16(
                        af[i], bfr[j], acc[i][j], 0, 0, 0);
        }
        __syncthreads();
    }

    // h = fast_tanh(acc + b1) -> bf16, swizzled [128][256] at lds[0..32768)
    float b1v[4];
    #pragma unroll
    for (int j = 0; j < 4; ++j)
        b1v[j] = b1[e * HDIM + wave * 64 + j * 16 + lr];

    #pragma unroll
    for (int i = 0; i < 8; ++i)
        #pragma unroll
        for (int j = 0; j < 4; ++j) {
            int c = wave * 64 + j * 16 + lr;
            int gg = c >> 3;
            #pragma unroll
            for (int rr = 0; rr < 4; ++rr) {
                int r = i * 16 + rq + rr;
                float v = fast_tanh(acc[i][j][rr] + b1v[j]);
                lds[r * 256 + (((gg & 24) | ((gg & 7) ^ (r & 7))) << 3) + (c & 7)] = f2bf(v);
            }
        }
    __syncthreads();

    // Phase B: y[128][64]; wave owns rows [wave*32, +32); W2 frags from global
    const ushort* w2 = W2T + (size_t)e * LDIM * HDIM;
    floatx4 acc2[2][4] = {};
    #pragma unroll
    for (int s = 0; s < 8; ++s) {
        int g = s * 4 + q;
        bf16x8 af[2];
        #pragma unroll
        for (int it = 0; it < 2; ++it) {
            int r = wave * 32 + it * 16 + lr;
            af[it] = *reinterpret_cast<const bf16x8*>(
                &lds[r * 256 + (((g & 24) | ((g & 7) ^ (r & 7))) << 3)]);
        }
        #pragma unroll
        for (int j = 0; j < 4; ++j) {
            bf16x8 bfr = *reinterpret_cast<const bf16x8*>(
                &w2[(size_t)(j * 16 + lr) * HDIM + s * 32 + kq]);
            #pragma unroll
            for (int it = 0; it < 2; ++it)
                acc2[it][j] = __builtin_amdgcn_mfma_f32_16x16x32_bf16(
                    af[it], bfr, acc2[it][j], 0, 0, 0);
        }
    }

    #pragma unroll
    for (int it = 0; it < 2; ++it)
        #pragma unroll
        for (int j = 0; j < 4; ++j) {
            float b2v = b2[e * LDIM + j * 16 + lr];
            #pragma unroll
            for (int rr = 0; rr < 4; ++rr) {
                int row = wave * 32 + it * 16 + rq + rr;
                float gsc = gates[(size_t)(row0 + row) * EEXP + e];
                out[(size_t)(row0 + row) * EEXP * LDIM + e * LDIM + j * 16 + lr] =
                    (acc2[it][j][rr] + b2v) * gsc;
            }
        }
}

// ---------------------------------------------------------------------------
extern "C" void kernel_launch(void* const* d_in, const int* in_sizes, int n_in,
                              void* d_out, int out_size, void* d_ws, size_t ws_size,
                              hipStream_t stream) {
    (void)in_sizes; (void)n_in; (void)out_size; (void)ws_size;
    const float* x     = (const float*)d_in[0];
    const float* noise = (const float*)d_in[1];
    const float* wg    = (const float*)d_in[2];
    const float* wn    = (const float*)d_in[3];
    const float* W1    = (const float*)d_in[4];
    const float* b1    = (const float*)d_in[5];
    const float* W2    = (const float*)d_in[6];
    const float* b2    = (const float*)d_in[7];
    float* out = (float*)d_out;

    char* ws = (char*)d_ws;
    float*  gates = (float*)ws;                    // 1 MiB
    ushort* W1T   = (ushort*)(ws + (1 << 20));     // 4 MiB
    ushort* W2T   = (ushort*)(ws + (5 << 20));     // 0.5 MiB
    ushort* xbf   = (ushort*)(ws + (6 << 20));     // 16 MiB

    gating_kernel<<<BROWS / 32, 256, 0, stream>>>(x, noise, wg, wn, gates, xbf);
    transpose_all<<<2048 + 256, 256, 0, stream>>>(W1, W1T, W2, W2T);
    expert_kernel<<<(BROWS / BM) * EEXP, 256, 0, stream>>>(
        xbf, gates, W1T, b1, W2T, b2, out);
}

// Round 6
// 186.812 us; speedup vs baseline: 1.7630x; 1.1732x over previous
//
#include <hip/hip_runtime.h>
#include <stdint.h>

#define BROWS 16384
#define DDIM  512
#define EEXP  16
#define HDIM  256
#define LDIM  64
#define BM    128

typedef __bf16  bf16x8  __attribute__((ext_vector_type(8)));
typedef float   floatx4 __attribute__((ext_vector_type(4)));
typedef ushort  ushort8 __attribute__((ext_vector_type(8)));
typedef unsigned int u32;

__device__ __forceinline__ ushort f2bf(float f) {
    uint32_t u = __builtin_bit_cast(uint32_t, f);
    u += 0x7fffu + ((u >> 16) & 1u);   // RNE
    return (ushort)(u >> 16);
}

// tanh(x) = 1 - 2/(exp2(2x*log2e)+1); saturates correctly, rel err ~1e-6.
__device__ __forceinline__ float fast_tanh(float x) {
    float e = __builtin_amdgcn_exp2f(x * 2.8853900817779268f);
    return 1.0f - 2.0f * __builtin_amdgcn_rcpf(e + 1.0f);
}

__device__ __forceinline__ void gl_lds16(const void* g, void* l) {
    __builtin_amdgcn_global_load_lds(
        (const __attribute__((address_space(1))) u32*)g,
        (__attribute__((address_space(3))) u32*)l, 16, 0, 0);
}

// ---------------------------------------------------------------------------
__global__ __launch_bounds__(64) void init_cnt(u32* __restrict__ cnt) {
    if (threadIdx.x < EEXP) cnt[threadIdx.x] = 0;
}

// ---------------------------------------------------------------------------
// Gating (f32, math identical to round 5) + fused x f32->bf16 swizzled cvt
// + per-expert active-row compaction (LDS-local lists, 16 global atomics/blk).
// 32 rows/block; thread = (rg 0..15, og 0..15): 2 rows x (wg,wn) each.
// ---------------------------------------------------------------------------
__global__ __launch_bounds__(256) void gating_kernel(
    const float* __restrict__ x,      // [B][D]
    const float* __restrict__ noise,  // [B][E]
    const float* __restrict__ wg,     // [D][E]
    const float* __restrict__ wn,     // [D][E]
    float* __restrict__ gates,        // [B][E]
    ushort* __restrict__ xbf,         // [B][D] bf16 swizzled
    u32* __restrict__ cnt,            // [E]
    u32* __restrict__ rowlist)        // [E][B]
{
    __shared__ __align__(16) float xs[32 * 132];    // 16.5 KB
    __shared__ __align__(16) float wTg[16 * 132];   // 8.25 KB
    __shared__ __align__(16) float wTn[16 * 132];   // 8.25 KB
    __shared__ u32 lcnt[16];
    __shared__ u32 gbase[16];
    __shared__ ushort lrows[16 * 32];

    const int t    = threadIdx.x;
    const int row0 = blockIdx.x * 32;
    const int og   = t & 15, rg = t >> 4;

    if (t < 16) lcnt[t] = 0;

    floatx4 accg4[2] = {}, accn4[2] = {};

    for (int ch = 0; ch < 4; ++ch) {
        const int k0 = ch * 128;
        __syncthreads();   // previous chunk's reads done before restage
        {   // stage xs[32][128] + fused bf16 swizzled writeback
            int r = t >> 3, c = (t & 7) * 16;
            const float* src = &x[(size_t)(row0 + r) * DDIM + k0 + c];
            float4 f[4];
            #pragma unroll
            for (int i = 0; i < 4; ++i)
                f[i] = reinterpret_cast<const float4*>(src)[i];
            float* dst = &xs[r * 132 + c];
            #pragma unroll
            for (int i = 0; i < 4; ++i)
                reinterpret_cast<float4*>(dst)[i] = f[i];

            const int row = row0 + r;
            const int sw  = r & 7;
            #pragma unroll
            for (int i = 0; i < 2; ++i) {
                int cb = k0 + c + i * 8;
                int kb = cb >> 6;
                int g  = (cb >> 3) & 7;
                int gp = g ^ sw;
                float4 a = f[i * 2], b = f[i * 2 + 1];
                ushort8 t8;
                t8[0]=f2bf(a.x); t8[1]=f2bf(a.y); t8[2]=f2bf(a.z); t8[3]=f2bf(a.w);
                t8[4]=f2bf(b.x); t8[5]=f2bf(b.y); t8[6]=f2bf(b.z); t8[7]=f2bf(b.w);
                *reinterpret_cast<ushort8*>(&xbf[(size_t)row * DDIM + kb * 64 + gp * 8]) = t8;
            }
        }
        {   // stage wTg/wTn transposed (pad 132 -> conflict-free reads)
            int d = t >> 1, e0 = (t & 1) * 8;
            float4 a0 = *reinterpret_cast<const float4*>(&wg[(size_t)(k0 + d) * EEXP + e0]);
            float4 a1 = *reinterpret_cast<const float4*>(&wg[(size_t)(k0 + d) * EEXP + e0 + 4]);
            float4 b0 = *reinterpret_cast<const float4*>(&wn[(size_t)(k0 + d) * EEXP + e0]);
            float4 b1 = *reinterpret_cast<const float4*>(&wn[(size_t)(k0 + d) * EEXP + e0 + 4]);
            wTg[(e0+0)*132+d]=a0.x; wTg[(e0+1)*132+d]=a0.y; wTg[(e0+2)*132+d]=a0.z; wTg[(e0+3)*132+d]=a0.w;
            wTg[(e0+4)*132+d]=a1.x; wTg[(e0+5)*132+d]=a1.y; wTg[(e0+6)*132+d]=a1.z; wTg[(e0+7)*132+d]=a1.w;
            wTn[(e0+0)*132+d]=b0.x; wTn[(e0+1)*132+d]=b0.y; wTn[(e0+2)*132+d]=b0.z; wTn[(e0+3)*132+d]=b0.w;
            wTn[(e0+4)*132+d]=b1.x; wTn[(e0+5)*132+d]=b1.y; wTn[(e0+6)*132+d]=b1.z; wTn[(e0+7)*132+d]=b1.w;
        }
        __syncthreads();

        #pragma unroll 8
        for (int d4 = 0; d4 < 32; ++d4) {
            floatx4 wgv = *reinterpret_cast<const floatx4*>(&wTg[og * 132 + d4 * 4]);
            floatx4 wnv = *reinterpret_cast<const floatx4*>(&wTn[og * 132 + d4 * 4]);
            #pragma unroll
            for (int rr = 0; rr < 2; ++rr) {
                floatx4 xv = *reinterpret_cast<const floatx4*>(&xs[(rg * 2 + rr) * 132 + d4 * 4]);
                accg4[rr] += xv * wgv;
                accn4[rr] += xv * wnv;
            }
        }
    }

    #pragma unroll
    for (int rr = 0; rr < 2; ++rr) {
        const int row = row0 + rg * 2 + rr;
        float accg = accg4[rr][0] + accg4[rr][1] + accg4[rr][2] + accg4[rr][3];
        float accn = accn4[rr][0] + accn4[rr][1] + accn4[rr][2] + accn4[rr][3];

        // keep libcall-precision softplus: gate threshold flips are the risk
        float sp = fmaxf(accn, 0.f) + log1pf(expf(-fabsf(accn)));
        float stddev = sp + 0.01f;
        float nz = noise[(size_t)row * EEXP + og];
        float z = accg + nz * stddev;

        float m = z;
        #pragma unroll
        for (int mask = 8; mask >= 1; mask >>= 1)
            m = fmaxf(m, __shfl_xor(m, mask, 16));
        float ez = expf(z - m);
        float s = ez;
        #pragma unroll
        for (int mask = 8; mask >= 1; mask >>= 1)
            s += __shfl_xor(s, mask, 16);
        float logit = ez / s;

        float lsum = logit;
        #pragma unroll
        for (int mask = 8; mask >= 1; mask >>= 1)
            lsum += __shfl_xor(lsum, mask, 16);
        float mean = lsum * (1.0f / 16.0f) - 1e-8f;

        float gate = (logit >= mean) ? logit : 0.0f;
        float denom = gate;
        #pragma unroll
        for (int mask = 8; mask >= 1; mask >>= 1)
            denom += __shfl_xor(denom, mask, 16);

        gates[(size_t)row * EEXP + og] = gate / denom;

        if (gate > 0.0f) {
            u32 p = atomicAdd(&lcnt[og], 1u);
            lrows[og * 32 + p] = (ushort)(rg * 2 + rr);
        }
    }

    __syncthreads();
    if (t < 16) gbase[t] = atomicAdd(&cnt[t], lcnt[t]);
    __syncthreads();
    for (int i = t; i < 16 * 32; i += 256) {
        int e = i >> 5, j = i & 31;
        if ((u32)j < lcnt[e])
            rowlist[(size_t)e * BROWS + gbase[e] + j] = row0 + lrows[e * 32 + j];
    }
}

// ---------------------------------------------------------------------------
// Zero-fill inactive output slots (gate == 0 exactly).
// ---------------------------------------------------------------------------
__global__ __launch_bounds__(256) void zero_fill(
    const float* __restrict__ gates, float* __restrict__ out)
{
    int i = blockIdx.x * 256 + threadIdx.x;   // one float4 per thread
    int slot = i >> 4;
    if (gates[slot] == 0.0f) {
        float4 z = {0.f, 0.f, 0.f, 0.f};
        reinterpret_cast<float4*>(out)[i] = z;
    }
}

// ---------------------------------------------------------------------------
// Both weight transposes in ONE launch (block-id range dispatch).
// W1 f32 [E][512][256] -> W1T bf16 [E][256][512] swizzled  (2048 blocks)
// W2 f32 [E][256][64]  -> W2T bf16 [E][64][256]  linear    (256 blocks)
// ---------------------------------------------------------------------------
__global__ __launch_bounds__(256) void transpose_all(
    const float* __restrict__ W1, ushort* __restrict__ W1T,
    const float* __restrict__ W2, ushort* __restrict__ W2T)
{
    __shared__ float tile[32][33];
    int b = blockIdx.x;
    const float* src; ushort* dst; int R, C, c0, r0, swz, ei;
    if (b < 2048) {
        ei = b >> 7; int rem = b & 127;
        c0 = (rem & 7) * 32; r0 = (rem >> 3) * 32;
        R = DDIM; C = HDIM; swz = 1;
        src = W1; dst = W1T;
    } else {
        b -= 2048;
        ei = b >> 4; int rem = b & 15;
        c0 = (rem & 1) * 32; r0 = (rem >> 1) * 32;
        R = HDIM; C = LDIM; swz = 0;
        src = W2; dst = W2T;
    }
    const int tx = threadIdx.x & 31, ty = threadIdx.x >> 5;
    const float* s = src + (size_t)ei * R * C;
    ushort* d = dst + (size_t)ei * R * C;

    #pragma unroll
    for (int i = 0; i < 4; ++i) {
        int rr = ty + i * 8;
        tile[rr][tx] = s[(size_t)(r0 + rr) * C + c0 + tx];
    }
    __syncthreads();
    #pragma unroll
    for (int i = 0; i < 4; ++i) {
        int cc = ty + i * 8;
        int h = c0 + cc;            // output row
        int col = r0 + tx;          // output col
        int col2 = col;
        if (swz) {
            int g = (col >> 3) & 7;
            col2 = (col & ~63) | ((g ^ (h & 7)) << 3) | (col & 7);
        }
        d[(size_t)h * R + col2] = f2bf(tile[tx][cc]);
    }
}

// ---------------------------------------------------------------------------
// Sparse expert MLP: block (e, t) processes rows rowlist[e][t*128 .. +128).
// Early-exit if tile beyond count[e]. A-tile gathered via per-lane row bases;
// swizzle re-keyed to LDS row via (la ^ ri&7) XOR on the global group index.
// ---------------------------------------------------------------------------
__global__ __launch_bounds__(256, 2) void expert_kernel(
    const ushort* __restrict__ xbf,    // [B][D] bf16, swizzled
    const float*  __restrict__ gates,  // [B][E]
    const ushort* __restrict__ W1T,    // [E][H][D] bf16, swizzled
    const float*  __restrict__ b1,     // [E][H]
    const ushort* __restrict__ W2T,    // [E][L][H] bf16, linear
    const float*  __restrict__ b2,     // [E][L]
    const u32*    __restrict__ cnt,    // [E]
    const u32*    __restrict__ rowlist,// [E][B]
    float* __restrict__ out)           // [B][E][L]
{
    __shared__ __align__(16) ushort lds[32768];

    const int bx   = blockIdx.x;
    const int e    = bx & 15;
    const int t    = bx >> 4;

    const int count = (int)cnt[e];
    if (t * BM >= count) return;
    const int nrt = min(BM, count - t * BM);
    const u32* rl = rowlist + (size_t)e * BROWS + t * BM;

    const int tid  = threadIdx.x;
    const int lane = tid & 63;
    const int wave = tid >> 6;

    const int lr = lane & 15;
    const int q  = lane >> 4;
    const int kq = q * 8;
    const int rq = q * 4;
    const int la = lane >> 3, lb = lane & 7;  // staging lane split

    const char* xg = (const char*)xbf;
    const char* w1 = (const char*)W1T + (size_t)e * HDIM * 1024;

    // Per-lane gathered A-row bases + swizzle re-key terms
    size_t abase[4]; int sxr[4];
    #pragma unroll
    for (int p = 0; p < 4; ++p) {
        int r  = wave * 32 + p * 8 + la;
        int rc = min(r, nrt - 1);
        u32 ri = rl[rc];
        abase[p] = (size_t)ri * 1024;
        sxr[p]   = (la ^ (int)(ri & 7)) << 4;
    }

    floatx4 acc[8][4] = {};

    for (int kb = 0; kb < 8; ++kb) {
        const int koff = kb * 128;   // byte offset within 1024-B row
        #pragma unroll
        for (int p = 0; p < 4; ++p) {   // A tile: 16 KB (gathered rows)
            int c = wave * 4 + p;
            gl_lds16(xg + abase[p] + koff + ((lb << 4) ^ sxr[p]), &lds[c * 512]);
        }
        #pragma unroll
        for (int p = 0; p < 8; ++p) {   // B tile: 32 KB (sequential W1T rows)
            int c = wave * 8 + p;
            gl_lds16(w1 + (size_t)(c * 8 + la) * 1024 + koff + (lb << 4), &lds[8192 + c * 512]);
        }
        __syncthreads();

        #pragma unroll
        for (int s = 0; s < 2; ++s) {
            const int g = s * 4 + q;
            bf16x8 af[8], bfr[4];
            #pragma unroll
            for (int i = 0; i < 8; ++i) {
                int r = i * 16 + lr;
                af[i] = *reinterpret_cast<const bf16x8*>(&lds[r * 64 + ((g ^ (r & 7)) << 3)]);
            }
            #pragma unroll
            for (int j = 0; j < 4; ++j) {
                int r = wave * 64 + j * 16 + lr;
                bfr[j] = *reinterpret_cast<const bf16x8*>(&lds[8192 + r * 64 + ((g ^ (r & 7)) << 3)]);
            }
            #pragma unroll
            for (int i = 0; i < 8; ++i)
                #pragma unroll
                for (int j = 0; j < 4; ++j)
                    acc[i][j] = __builtin_amdgcn_mfma_f32_16x16x32_bf16(
                        af[i], bfr[j], acc[i][j], 0, 0, 0);
        }
        __syncthreads();
    }

    // h = fast_tanh(acc + b1) -> bf16, swizzled [128][256] at lds[0..32768)
    float b1v[4];
    #pragma unroll
    for (int j = 0; j < 4; ++j)
        b1v[j] = b1[e * HDIM + wave * 64 + j * 16 + lr];

    #pragma unroll
    for (int i = 0; i < 8; ++i)
        #pragma unroll
        for (int j = 0; j < 4; ++j) {
            int c = wave * 64 + j * 16 + lr;
            int gg = c >> 3;
            #pragma unroll
            for (int rr = 0; rr < 4; ++rr) {
                int r = i * 16 + rq + rr;
                float v = fast_tanh(acc[i][j][rr] + b1v[j]);
                lds[r * 256 + (((gg & 24) | ((gg & 7) ^ (r & 7))) << 3) + (c & 7)] = f2bf(v);
            }
        }
    __syncthreads();

    // Phase B: y[128][64]; wave owns rows [wave*32, +32); W2 frags from global
    const ushort* w2 = W2T + (size_t)e * LDIM * HDIM;
    floatx4 acc2[2][4] = {};
    #pragma unroll
    for (int s = 0; s < 8; ++s) {
        int g = s * 4 + q;
        bf16x8 af[2];
        #pragma unroll
        for (int it = 0; it < 2; ++it) {
            int r = wave * 32 + it * 16 + lr;
            af[it] = *reinterpret_cast<const bf16x8*>(
                &lds[r * 256 + (((g & 24) | ((g & 7) ^ (r & 7))) << 3)]);
        }
        #pragma unroll
        for (int j = 0; j < 4; ++j) {
            bf16x8 bfr = *reinterpret_cast<const bf16x8*>(
                &w2[(size_t)(j * 16 + lr) * HDIM + s * 32 + kq]);
            #pragma unroll
            for (int it = 0; it < 2; ++it)
                acc2[it][j] = __builtin_amdgcn_mfma_f32_16x16x32_bf16(
                    af[it], bfr, acc2[it][j], 0, 0, 0);
        }
    }

    float b2v[4];
    #pragma unroll
    for (int j = 0; j < 4; ++j)
        b2v[j] = b2[e * LDIM + j * 16 + lr];

    #pragma unroll
    for (int it = 0; it < 2; ++it)
        #pragma unroll
        for (int rr = 0; rr < 4; ++rr) {
            int r  = wave * 32 + it * 16 + rq + rr;
            int rc = min(r, nrt - 1);
            u32 ri = rl[rc];
            float gsc = gates[(size_t)ri * EEXP + e];
            if (r < nrt) {
                #pragma unroll
                for (int j = 0; j < 4; ++j)
                    out[(size_t)ri * (EEXP * LDIM) + e * LDIM + j * 16 + lr] =
                        (acc2[it][j][rr] + b2v[j]) * gsc;
            }
        }
}

// ---------------------------------------------------------------------------
extern "C" void kernel_launch(void* const* d_in, const int* in_sizes, int n_in,
                              void* d_out, int out_size, void* d_ws, size_t ws_size,
                              hipStream_t stream) {
    (void)in_sizes; (void)n_in; (void)out_size; (void)ws_size;
    const float* x     = (const float*)d_in[0];
    const float* noise = (const float*)d_in[1];
    const float* wg    = (const float*)d_in[2];
    const float* wn    = (const float*)d_in[3];
    const float* W1    = (const float*)d_in[4];
    const float* b1    = (const float*)d_in[5];
    const float* W2    = (const float*)d_in[6];
    const float* b2    = (const float*)d_in[7];
    float* out = (float*)d_out;

    char* ws = (char*)d_ws;
    float*  gates   = (float*)ws;                    // 1 MiB
    ushort* W1T     = (ushort*)(ws + (1 << 20));     // 4 MiB
    ushort* W2T     = (ushort*)(ws + (5 << 20));     // 0.5 MiB
    ushort* xbf     = (ushort*)(ws + (6 << 20));     // 16 MiB
    u32*    cnt     = (u32*)(ws + (22 << 20));       // 64 B
    u32*    rowlist = (u32*)(ws + (22 << 20) + 4096);// 1 MiB

    init_cnt<<<1, 64, 0, stream>>>(cnt);
    gating_kernel<<<BROWS / 32, 256, 0, stream>>>(x, noise, wg, wn, gates, xbf, cnt, rowlist);
    transpose_all<<<2048 + 256, 256, 0, stream>>>(W1, W1T, W2, W2T);
    zero_fill<<<(BROWS * EEXP * LDIM / 4) / 256, 256, 0, stream>>>(gates, out);
    expert_kernel<<<(BROWS / BM) * EEXP, 256, 0, stream>>>(
        xbf, gates, W1T, b1, W2T, b2, cnt, rowlist, out);
}

// Round 7
// 184.359 us; speedup vs baseline: 1.7864x; 1.0133x over previous
//
#include <hip/hip_runtime.h>
#include <stdint.h>

#define BROWS 16384
#define DDIM  512
#define EEXP  16
#define HDIM  256
#define LDIM  64
#define BM    64

typedef __bf16  bf16x8  __attribute__((ext_vector_type(8)));
typedef float   floatx4 __attribute__((ext_vector_type(4)));
typedef ushort  ushort8 __attribute__((ext_vector_type(8)));
typedef unsigned int u32;

__device__ __forceinline__ ushort f2bf(float f) {
    uint32_t u = __builtin_bit_cast(uint32_t, f);
    u += 0x7fffu + ((u >> 16) & 1u);   // RNE
    return (ushort)(u >> 16);
}

// tanh(x) = 1 - 2/(exp2(2x*log2e)+1); saturates correctly, rel err ~1e-6.
__device__ __forceinline__ float fast_tanh(float x) {
    float e = __builtin_amdgcn_exp2f(x * 2.8853900817779268f);
    return 1.0f - 2.0f * __builtin_amdgcn_rcpf(e + 1.0f);
}

__device__ __forceinline__ void gl_lds16(const void* g, void* l) {
    __builtin_amdgcn_global_load_lds(
        (const __attribute__((address_space(1))) u32*)g,
        (__attribute__((address_space(3))) u32*)l, 16, 0, 0);
}

// ---------------------------------------------------------------------------
// Gating (f32, math unchanged) + fused x f32->bf16 swizzled cvt
// + per-(expert, gating-block) row slots (NO global atomics -> sortable).
// 32 rows/block; thread = (rg 0..15, og 0..15): 2 rows x (wg,wn) each.
// ---------------------------------------------------------------------------
__global__ __launch_bounds__(256) void gating_kernel(
    const float* __restrict__ x,      // [B][D]
    const float* __restrict__ noise,  // [B][E]
    const float* __restrict__ wg,     // [D][E]
    const float* __restrict__ wn,     // [D][E]
    float* __restrict__ gates,        // [B][E]
    ushort* __restrict__ xbf,         // [B][D] bf16 swizzled
    u32* __restrict__ cntb,           // [E][512] per-block counts
    u32* __restrict__ rowtmp)         // [E][512*32] slotted rows
{
    __shared__ __align__(16) float xs[32 * 132];    // 16.5 KB
    __shared__ __align__(16) float wTg[16 * 132];   // 8.25 KB
    __shared__ __align__(16) float wTn[16 * 132];   // 8.25 KB
    __shared__ u32 lcnt[16];
    __shared__ ushort lrows[16 * 32];

    const int t    = threadIdx.x;
    const int blk  = blockIdx.x;
    const int row0 = blk * 32;
    const int og   = t & 15, rg = t >> 4;

    if (t < 16) lcnt[t] = 0;

    floatx4 accg4[2] = {}, accn4[2] = {};

    for (int ch = 0; ch < 4; ++ch) {
        const int k0 = ch * 128;
        __syncthreads();
        {   // stage xs[32][128] + fused bf16 swizzled writeback
            int r = t >> 3, c = (t & 7) * 16;
            const float* src = &x[(size_t)(row0 + r) * DDIM + k0 + c];
            float4 f[4];
            #pragma unroll
            for (int i = 0; i < 4; ++i)
                f[i] = reinterpret_cast<const float4*>(src)[i];
            float* dst = &xs[r * 132 + c];
            #pragma unroll
            for (int i = 0; i < 4; ++i)
                reinterpret_cast<float4*>(dst)[i] = f[i];

            const int row = row0 + r;
            const int sw  = r & 7;
            #pragma unroll
            for (int i = 0; i < 2; ++i) {
                int cb = k0 + c + i * 8;
                int kb = cb >> 6;
                int g  = (cb >> 3) & 7;
                int gp = g ^ sw;
                float4 a = f[i * 2], b = f[i * 2 + 1];
                ushort8 t8;
                t8[0]=f2bf(a.x); t8[1]=f2bf(a.y); t8[2]=f2bf(a.z); t8[3]=f2bf(a.w);
                t8[4]=f2bf(b.x); t8[5]=f2bf(b.y); t8[6]=f2bf(b.z); t8[7]=f2bf(b.w);
                *reinterpret_cast<ushort8*>(&xbf[(size_t)row * DDIM + kb * 64 + gp * 8]) = t8;
            }
        }
        {   // stage wTg/wTn transposed (pad 132 -> conflict-free reads)
            int d = t >> 1, e0 = (t & 1) * 8;
            float4 a0 = *reinterpret_cast<const float4*>(&wg[(size_t)(k0 + d) * EEXP + e0]);
            float4 a1 = *reinterpret_cast<const float4*>(&wg[(size_t)(k0 + d) * EEXP + e0 + 4]);
            float4 b0 = *reinterpret_cast<const float4*>(&wn[(size_t)(k0 + d) * EEXP + e0]);
            float4 b1 = *reinterpret_cast<const float4*>(&wn[(size_t)(k0 + d) * EEXP + e0 + 4]);
            wTg[(e0+0)*132+d]=a0.x; wTg[(e0+1)*132+d]=a0.y; wTg[(e0+2)*132+d]=a0.z; wTg[(e0+3)*132+d]=a0.w;
            wTg[(e0+4)*132+d]=a1.x; wTg[(e0+5)*132+d]=a1.y; wTg[(e0+6)*132+d]=a1.z; wTg[(e0+7)*132+d]=a1.w;
            wTn[(e0+0)*132+d]=b0.x; wTn[(e0+1)*132+d]=b0.y; wTn[(e0+2)*132+d]=b0.z; wTn[(e0+3)*132+d]=b0.w;
            wTn[(e0+4)*132+d]=b1.x; wTn[(e0+5)*132+d]=b1.y; wTn[(e0+6)*132+d]=b1.z; wTn[(e0+7)*132+d]=b1.w;
        }
        __syncthreads();

        #pragma unroll 8
        for (int d4 = 0; d4 < 32; ++d4) {
            floatx4 wgv = *reinterpret_cast<const floatx4*>(&wTg[og * 132 + d4 * 4]);
            floatx4 wnv = *reinterpret_cast<const floatx4*>(&wTn[og * 132 + d4 * 4]);
            #pragma unroll
            for (int rr = 0; rr < 2; ++rr) {
                floatx4 xv = *reinterpret_cast<const floatx4*>(&xs[(rg * 2 + rr) * 132 + d4 * 4]);
                accg4[rr] += xv * wgv;
                accn4[rr] += xv * wnv;
            }
        }
    }

    #pragma unroll
    for (int rr = 0; rr < 2; ++rr) {
        const int row = row0 + rg * 2 + rr;
        float accg = accg4[rr][0] + accg4[rr][1] + accg4[rr][2] + accg4[rr][3];
        float accn = accn4[rr][0] + accn4[rr][1] + accn4[rr][2] + accn4[rr][3];

        // keep libcall-precision softplus: gate threshold flips are the risk
        float sp = fmaxf(accn, 0.f) + log1pf(expf(-fabsf(accn)));
        float stddev = sp + 0.01f;
        float nz = noise[(size_t)row * EEXP + og];
        float z = accg + nz * stddev;

        float m = z;
        #pragma unroll
        for (int mask = 8; mask >= 1; mask >>= 1)
            m = fmaxf(m, __shfl_xor(m, mask, 16));
        float ez = expf(z - m);
        float s = ez;
        #pragma unroll
        for (int mask = 8; mask >= 1; mask >>= 1)
            s += __shfl_xor(s, mask, 16);
        float logit = ez / s;

        float lsum = logit;
        #pragma unroll
        for (int mask = 8; mask >= 1; mask >>= 1)
            lsum += __shfl_xor(lsum, mask, 16);
        float mean = lsum * (1.0f / 16.0f) - 1e-8f;

        float gate = (logit >= mean) ? logit : 0.0f;
        float denom = gate;
        #pragma unroll
        for (int mask = 8; mask >= 1; mask >>= 1)
            denom += __shfl_xor(denom, mask, 16);

        gates[(size_t)row * EEXP + og] = gate / denom;

        if (gate > 0.0f) {
            u32 p = atomicAdd(&lcnt[og], 1u);
            lrows[og * 32 + p] = (ushort)(rg * 2 + rr);
        }
    }

    __syncthreads();
    if (t < 16) cntb[t * 512 + blk] = lcnt[t];
    for (int i = t; i < 16 * 32; i += 256) {
        int e = i >> 5, j = i & 31;
        if ((u32)j < lcnt[e])
            rowtmp[(size_t)e * 16384 + blk * 32 + j] = row0 + lrows[e * 32 + j];
    }
}

// ---------------------------------------------------------------------------
// Compaction: block b (512 total) computes bases[e][b] = sum cntb[e][0..b)
// redundantly (wave-parallel, L2-hot), then copies its <=32 rows per expert
// into the globally SORTED rowlist. Block 511 also writes cnt[e].
// ---------------------------------------------------------------------------
__global__ __launch_bounds__(256) void compact_kernel(
    const u32* __restrict__ cntb,     // [E][512]
    const u32* __restrict__ rowtmp,   // [E][512*32]
    u32* __restrict__ rowlist,        // [E][B] sorted
    u32* __restrict__ cnt)            // [E]
{
    __shared__ u32 base_s[16];
    const int b    = blockIdx.x;
    const int lane = threadIdx.x & 63;
    const int wave = threadIdx.x >> 6;

    for (int e = wave; e < 16; e += 4) {
        u32 s = 0;
        for (int i = lane; i < b; i += 64) s += cntb[e * 512 + i];
        #pragma unroll
        for (int off = 32; off; off >>= 1) s += __shfl_down(s, off, 64);
        if (lane == 0) {
            base_s[e] = s;
            if (b == 511) cnt[e] = s + cntb[e * 512 + 511];
        }
    }
    __syncthreads();

    const int t = threadIdx.x;
    for (int i = t; i < 512; i += 256) {
        int e = i >> 5, j = i & 31;
        if ((u32)j < cntb[e * 512 + b])
            rowlist[(size_t)e * BROWS + base_s[e] + j] =
                rowtmp[(size_t)e * 16384 + b * 32 + j];
    }
}

// ---------------------------------------------------------------------------
// Merged aux kernel: W1/W2 transpose+cvt (blocks 0..2303) and zero-fill of
// inactive out slots (blocks 2304..18687). Runs after gating (needs gates).
// ---------------------------------------------------------------------------
__global__ __launch_bounds__(256) void aux_kernel(
    const float* __restrict__ W1, ushort* __restrict__ W1T,
    const float* __restrict__ W2, ushort* __restrict__ W2T,
    const float* __restrict__ gates, float* __restrict__ out)
{
    int b = blockIdx.x;
    if (b >= 2304) {   // zero-fill: one float4 per thread
        int i = (b - 2304) * 256 + threadIdx.x;
        int slot = i >> 4;
        if (gates[slot] == 0.0f) {
            float4 z = {0.f, 0.f, 0.f, 0.f};
            reinterpret_cast<float4*>(out)[i] = z;
        }
        return;
    }
    __shared__ float tile[32][33];
    const float* src; ushort* dst; int R, C, c0, r0, swz, ei;
    if (b < 2048) {
        ei = b >> 7; int rem = b & 127;
        c0 = (rem & 7) * 32; r0 = (rem >> 3) * 32;
        R = DDIM; C = HDIM; swz = 1;
        src = W1; dst = W1T;
    } else {
        b -= 2048;
        ei = b >> 4; int rem = b & 15;
        c0 = (rem & 1) * 32; r0 = (rem >> 1) * 32;
        R = HDIM; C = LDIM; swz = 0;
        src = W2; dst = W2T;
    }
    const int tx = threadIdx.x & 31, ty = threadIdx.x >> 5;
    const float* s = src + (size_t)ei * R * C;
    ushort* d = dst + (size_t)ei * R * C;

    #pragma unroll
    for (int i = 0; i < 4; ++i) {
        int rr = ty + i * 8;
        tile[rr][tx] = s[(size_t)(r0 + rr) * C + c0 + tx];
    }
    __syncthreads();
    #pragma unroll
    for (int i = 0; i < 4; ++i) {
        int cc = ty + i * 8;
        int h = c0 + cc;
        int col = r0 + tx;
        int col2 = col;
        if (swz) {
            int g = (col >> 3) & 7;
            col2 = (col & ~63) | ((g ^ (h & 7)) << 3) | (col & 7);
        }
        d[(size_t)h * R + col2] = f2bf(tile[tx][cc]);
    }
}

// ---------------------------------------------------------------------------
// Sparse expert MLP, BM=64, 40 KB LDS -> 4 blocks/CU. Block (e,t) processes
// sorted rows rowlist[e][t*64 .. +64) -> L2-local gather.
// ---------------------------------------------------------------------------
__global__ __launch_bounds__(256, 4) void expert_kernel(
    const ushort* __restrict__ xbf,    // [B][D] bf16, swizzled
    const float*  __restrict__ gates,  // [B][E]
    const ushort* __restrict__ W1T,    // [E][H][D] bf16, swizzled
    const float*  __restrict__ b1,     // [E][H]
    const ushort* __restrict__ W2T,    // [E][L][H] bf16, linear
    const float*  __restrict__ b2,     // [E][L]
    const u32*    __restrict__ cnt,    // [E]
    const u32*    __restrict__ rowlist,// [E][B] sorted
    float* __restrict__ out)           // [B][E][L]
{
    __shared__ __align__(16) ushort lds[20480];  // A [0,8K)B, B [8K,40K)B; h [0,32K)B

    const int bx = blockIdx.x;
    const int e  = bx & 15;
    const int t  = bx >> 4;

    const int count = (int)cnt[e];
    if (t * BM >= count) return;
    const int nrt = min(BM, count - t * BM);
    const u32* rl = rowlist + (size_t)e * BROWS + t * BM;

    const int tid  = threadIdx.x;
    const int lane = tid & 63;
    const int wave = tid >> 6;

    const int lr = lane & 15;
    const int q  = lane >> 4;
    const int kq = q * 8;
    const int rq = q * 4;
    const int la = lane >> 3, lb = lane & 7;  // staging lane split

    const char* xg = (const char*)xbf;
    const char* w1 = (const char*)W1T + (size_t)e * HDIM * 1024;

    // Per-lane gathered A-row bases + swizzle re-key terms
    size_t abase[2]; int sxr[2];
    #pragma unroll
    for (int p = 0; p < 2; ++p) {
        int r  = wave * 16 + p * 8 + la;
        int rc = min(r, nrt - 1);
        u32 ri = rl[rc];
        abase[p] = (size_t)ri * 1024;
        sxr[p]   = (la ^ (int)(ri & 7)) << 4;
    }

    floatx4 acc[4][4] = {};

    for (int kb = 0; kb < 8; ++kb) {
        const int koff = kb * 128;   // byte offset within 1024-B row
        #pragma unroll
        for (int p = 0; p < 2; ++p) {   // A tile: 8 KB (gathered rows)
            int c = wave * 2 + p;
            gl_lds16(xg + abase[p] + koff + ((lb << 4) ^ sxr[p]), &lds[c * 512]);
        }
        #pragma unroll
        for (int p = 0; p < 8; ++p) {   // B tile: 32 KB (sequential W1T rows)
            int c = wave * 8 + p;
            gl_lds16(w1 + (size_t)(c * 8 + la) * 1024 + koff + (lb << 4),
                     &lds[4096 + c * 512]);
        }
        __syncthreads();

        #pragma unroll
        for (int s = 0; s < 2; ++s) {
            const int g = s * 4 + q;
            bf16x8 af[4], bfr[4];
            #pragma unroll
            for (int i = 0; i < 4; ++i) {
                int r = i * 16 + lr;
                af[i] = *reinterpret_cast<const bf16x8*>(&lds[r * 64 + ((g ^ (r & 7)) << 3)]);
            }
            #pragma unroll
            for (int j = 0; j < 4; ++j) {
                int r = wave * 64 + j * 16 + lr;
                bfr[j] = *reinterpret_cast<const bf16x8*>(&lds[4096 + r * 64 + ((g ^ (r & 7)) << 3)]);
            }
            #pragma unroll
            for (int i = 0; i < 4; ++i)
                #pragma unroll
                for (int j = 0; j < 4; ++j)
                    acc[i][j] = __builtin_amdgcn_mfma_f32_16x16x32_bf16(
                        af[i], bfr[j], acc[i][j], 0, 0, 0);
        }
        __syncthreads();
    }

    // h = fast_tanh(acc + b1) -> bf16, swizzled [64][256] at lds[0..32K)
    float b1v[4];
    #pragma unroll
    for (int j = 0; j < 4; ++j)
        b1v[j] = b1[e * HDIM + wave * 64 + j * 16 + lr];

    #pragma unroll
    for (int i = 0; i < 4; ++i)
        #pragma unroll
        for (int j = 0; j < 4; ++j) {
            int c = wave * 64 + j * 16 + lr;
            int gg = c >> 3;
            #pragma unroll
            for (int rr = 0; rr < 4; ++rr) {
                int r = i * 16 + rq + rr;
                float v = fast_tanh(acc[i][j][rr] + b1v[j]);
                lds[r * 256 + (((gg & 24) | ((gg & 7) ^ (r & 7))) << 3) + (c & 7)] = f2bf(v);
            }
        }
    __syncthreads();

    // Phase B: y[64][64]; wave owns rows [wave*16,+16); W2 frags from global
    const ushort* w2 = W2T + (size_t)e * LDIM * HDIM;
    floatx4 acc2[4] = {};
    #pragma unroll
    for (int s = 0; s < 8; ++s) {
        int r = wave * 16 + lr;
        int g = s * 4 + q;
        bf16x8 af = *reinterpret_cast<const bf16x8*>(
            &lds[r * 256 + (((g & 24) | ((g & 7) ^ (r & 7))) << 3)]);
        #pragma unroll
        for (int j = 0; j < 4; ++j) {
            bf16x8 bfr = *reinterpret_cast<const bf16x8*>(
                &w2[(size_t)(j * 16 + lr) * HDIM + s * 32 + kq]);
            acc2[j] = __builtin_amdgcn_mfma_f32_16x16x32_bf16(af, bfr, acc2[j], 0, 0, 0);
        }
    }

    float b2v[4];
    #pragma unroll
    for (int j = 0; j < 4; ++j)
        b2v[j] = b2[e * LDIM + j * 16 + lr];

    #pragma unroll
    for (int rr = 0; rr < 4; ++rr) {
        int r  = wave * 16 + rq + rr;
        int rc = min(r, nrt - 1);
        u32 ri = rl[rc];
        float gsc = gates[(size_t)ri * EEXP + e];
        if (r < nrt) {
            #pragma unroll
            for (int j = 0; j < 4; ++j)
                out[(size_t)ri * (EEXP * LDIM) + e * LDIM + j * 16 + lr] =
                    (acc2[j][rr] + b2v[j]) * gsc;
        }
    }
}

// ---------------------------------------------------------------------------
extern "C" void kernel_launch(void* const* d_in, const int* in_sizes, int n_in,
                              void* d_out, int out_size, void* d_ws, size_t ws_size,
                              hipStream_t stream) {
    (void)in_sizes; (void)n_in; (void)out_size; (void)ws_size;
    const float* x     = (const float*)d_in[0];
    const float* noise = (const float*)d_in[1];
    const float* wg    = (const float*)d_in[2];
    const float* wn    = (const float*)d_in[3];
    const float* W1    = (const float*)d_in[4];
    const float* b1    = (const float*)d_in[5];
    const float* W2    = (const float*)d_in[6];
    const float* b2    = (const float*)d_in[7];
    float* out = (float*)d_out;

    char* ws = (char*)d_ws;
    float*  gates   = (float*)ws;                          // 1 MiB
    ushort* W1T     = (ushort*)(ws + (1 << 20));           // 4 MiB
    ushort* W2T     = (ushort*)(ws + (5 << 20));           // 0.5 MiB
    ushort* xbf     = (ushort*)(ws + (6 << 20));           // 16 MiB
    u32*    cntb    = (u32*)(ws + (22 << 20));             // 32 KiB
    u32*    cnt     = (u32*)(ws + (22 << 20) + (32 << 10));// 64 B
    u32*    rowtmp  = (u32*)(ws + (23 << 20));             // 1 MiB
    u32*    rowlist = (u32*)(ws + (24 << 20));             // 1 MiB

    gating_kernel<<<BROWS / 32, 256, 0, stream>>>(x, noise, wg, wn, gates, xbf, cntb, rowtmp);
    compact_kernel<<<512, 256, 0, stream>>>(cntb, rowtmp, rowlist, cnt);
    aux_kernel<<<2304 + 16384, 256, 0, stream>>>(W1, W1T, W2, W2T, gates, out);
    expert_kernel<<<(BROWS / BM) * EEXP, 256, 0, stream>>>(
        xbf, gates, W1T, b1, W2T, b2, cnt, rowlist, out);
}